// Round 1
// baseline (786.874 us; speedup 1.0000x reference)
//
#include <hip/hip_runtime.h>
#include <math.h>

#define S_ 64
#define N_ 256
#define L_ 32
#define D_ 128
#define LID_ 256
#define K1_ 17
#define SL 129  // padded LDS stride (129%32==1 -> conflict-free row access)

// ---------------------------------------------------------------- KNN kernel
// one wave (64 lanes) per (s,n); each lane owns 4 candidate j's.
// 17 iterations of argmin with (d, idx) lexicographic tie-break
// (matches jax.lax.top_k stable lower-index-first tie behavior).
__global__ __launch_bounds__(64) void tar_knn_kernel(
    const float* __restrict__ coord, int* __restrict__ idx_out,
    float* __restrict__ rel10_out) {
  int b = blockIdx.x;  // s*N + n
  int s = b >> 8;
  int n = b & 255;
  int lane = threadIdx.x;
  const float* cs = coord + (size_t)s * N_ * 3;
  float cx = cs[n * 3 + 0], cy = cs[n * 3 + 1], cz = cs[n * 3 + 2];
  float d[4];
  int jj[4];
#pragma unroll
  for (int q = 0; q < 4; ++q) {
    int j = q * 64 + lane;
    float dx = cs[j * 3 + 0] - cx;
    float dy = cs[j * 3 + 1] - cy;
    float dz = cs[j * 3 + 2] - cz;
    d[q] = dx * dx + dy * dy + dz * dz;
    jj[q] = j;
  }
  for (int k = 0; k < K1_; ++k) {
    float bd = 1e30f;
    int bj = 1 << 30;
#pragma unroll
    for (int q = 0; q < 4; ++q) {
      if (d[q] < bd || (d[q] == bd && jj[q] < bj)) { bd = d[q]; bj = jj[q]; }
    }
    for (int off = 32; off > 0; off >>= 1) {
      float od = __shfl_xor(bd, off);
      int oj = __shfl_xor(bj, off);
      if (od < bd || (od == bd && oj < bj)) { bd = od; bj = oj; }
    }
#pragma unroll
    for (int q = 0; q < 4; ++q)
      if (jj[q] == bj) d[q] = 1e30f;  // remove winner
    if (lane == 0) {
      idx_out[(size_t)b * K1_ + k] = bj;
      float nx = cs[bj * 3 + 0], ny = cs[bj * 3 + 1], nz = cs[bj * 3 + 2];
      float rx = nx - cx, ry = ny - cy, rz = nz - cz;
      float dist = sqrtf(rx * rx + ry * ry + rz * rz);
      float* r = rel10_out + ((size_t)b * K1_ + k) * 10;
      r[0] = nx; r[1] = ny; r[2] = nz;
      r[3] = cx; r[4] = cy; r[5] = cz;
      r[6] = rx; r[7] = ry; r[8] = rz; r[9] = dist;
    }
  }
}

// ---------------------------------------------------------------- lang MLP
// one block (128 threads) per row: 256 -> relu 128 -> 128
__global__ __launch_bounds__(128) void tar_lang_mlp_kernel(
    const float* __restrict__ x, const float* __restrict__ w1,
    const float* __restrict__ b1, const float* __restrict__ w2,
    const float* __restrict__ b2, float* __restrict__ y) {
  __shared__ float sx[LID_];
  __shared__ float sh[D_];
  int row = blockIdx.x, j = threadIdx.x;
  const float* xr = x + (size_t)row * LID_;
  sx[j] = xr[j];
  sx[j + 128] = xr[j + 128];
  __syncthreads();
  float acc = b1[j];
#pragma unroll 8
  for (int i = 0; i < LID_; ++i) acc += sx[i] * w1[i * D_ + j];
  sh[j] = fmaxf(acc, 0.f);
  __syncthreads();
  float acc2 = b2[j];
#pragma unroll 8
  for (int h = 0; h < D_; ++h) acc2 += sh[h] * w2[h * D_ + j];
  y[(size_t)row * D_ + j] = acc2;
}

// ---------------------------------------------------------------- feat MLP
// 8 rows per block (amortize weight reads): 128 -> relu 128 -> 128
__global__ __launch_bounds__(128) void tar_f_mlp_kernel(
    const float* __restrict__ x, const float* __restrict__ w1,
    const float* __restrict__ b1, const float* __restrict__ w2,
    const float* __restrict__ b2, float* __restrict__ y) {
  __shared__ float sx[8][D_];
  __shared__ float sh[8][D_];
  int base = blockIdx.x * 8, j = threadIdx.x;
  for (int r = 0; r < 8; ++r) sx[r][j] = x[(size_t)(base + r) * D_ + j];
  __syncthreads();
  float acc[8];
  float bb = b1[j];
#pragma unroll
  for (int r = 0; r < 8; ++r) acc[r] = bb;
  for (int i = 0; i < D_; ++i) {
    float w = w1[i * D_ + j];
#pragma unroll
    for (int r = 0; r < 8; ++r) acc[r] += sx[r][i] * w;
  }
#pragma unroll
  for (int r = 0; r < 8; ++r) sh[r][j] = fmaxf(acc[r], 0.f);
  __syncthreads();
  float bb2 = b2[j];
#pragma unroll
  for (int r = 0; r < 8; ++r) acc[r] = bb2;
  for (int h = 0; h < D_; ++h) {
    float w = w2[h * D_ + j];
#pragma unroll
    for (int r = 0; r < 8; ++r) acc[r] += sh[r][h] * w;
  }
#pragma unroll
  for (int r = 0; r < 8; ++r) y[(size_t)(base + r) * D_ + j] = acc[r];
}

// ---------------------------------------------------------------- main fused
// one block (128 threads) per (s,n): rel MLP + attn + softmax + PV + combine
__global__ __launch_bounds__(128) void tar_main_kernel(
    const float* __restrict__ f, const float* __restrict__ lang,
    const int* __restrict__ idx, const float* __restrict__ rel10,
    const float* __restrict__ rel_w1, const float* __restrict__ rel_b1,
    const float* __restrict__ rel_w2, const float* __restrict__ rel_b2,
    const int* __restrict__ lang_len, float* __restrict__ out,
    float* __restrict__ score) {
  __shared__ float s_lang[L_][SL];
  __shared__ float s_fnb[K1_][SL];
  __shared__ float s_relh[K1_][SL];
  __shared__ float s_relo[K1_][SL];
  __shared__ float s_attn[K1_][36];
  __shared__ float s_f[D_];
  __shared__ float s_r10[K1_ * 10];
  __shared__ int s_idx[K1_];
  __shared__ float s_red[2];

  int b = blockIdx.x;  // s*N + n
  int sI = b >> 8;
  int tid = threadIdx.x;

  for (int i = tid; i < L_ * D_; i += 128)
    s_lang[i >> 7][i & 127] = lang[(size_t)sI * L_ * D_ + i];
  if (tid < K1_) s_idx[tid] = idx[(size_t)b * K1_ + tid];
  for (int i = tid; i < K1_ * 10; i += 128)
    s_r10[i] = rel10[(size_t)b * K1_ * 10 + i];
  s_f[tid] = f[(size_t)b * D_ + tid];
  __syncthreads();

  // gather f_nb (own column)
  for (int k = 0; k < K1_; ++k)
    s_fnb[k][tid] = f[((size_t)(b & ~255) + s_idx[k]) * D_ + tid];

  // rel hidden layer: 10 -> 128 relu (thread j owns output feature j)
  {
    float w[10];
#pragma unroll
    for (int i = 0; i < 10; ++i) w[i] = rel_w1[i * D_ + tid];
    float bb = rel_b1[tid];
    for (int k = 0; k < K1_; ++k) {
      float a = bb;
#pragma unroll
      for (int i = 0; i < 10; ++i) a += s_r10[k * 10 + i] * w[i];
      s_relh[k][tid] = fmaxf(a, 0.f);
    }
  }
  __syncthreads();

  // rel output layer: 128 -> 128 (17 rows per thread, w2 column in reg)
  {
    float acc[K1_];
    float bb = rel_b2[tid];
#pragma unroll
    for (int k = 0; k < K1_; ++k) acc[k] = bb;
    for (int h = 0; h < D_; ++h) {
      float w = rel_w2[h * D_ + tid];
#pragma unroll
      for (int k = 0; k < K1_; ++k) acc[k] += s_relh[k][h] * w;
    }
#pragma unroll
    for (int k = 0; k < K1_; ++k) s_relo[k][tid] = acc[k];
  }

  // attn scores: 544 (k,l) pairs over 128 threads, dot over D
  for (int p = tid; p < K1_ * L_; p += 128) {
    int k = p >> 5, l = p & 31;
    float a = 0.f;
#pragma unroll 8
    for (int dd = 0; dd < D_; ++dd) a += s_fnb[k][dd] * s_lang[l][dd];
    s_attn[k][l] = a;
  }
  __syncthreads();

  // softmax over all 32 tokens, then mask, then renorm with +1e-7 (ref exact)
  if (tid < K1_) {
    int len = lang_len[sI];
    float m = -1e30f;
#pragma unroll
    for (int l = 0; l < L_; ++l) m = fmaxf(m, s_attn[tid][l]);
    float ssum = 0.f;
#pragma unroll
    for (int l = 0; l < L_; ++l) {
      float e = expf(s_attn[tid][l] - m);
      s_attn[tid][l] = e;
      ssum += e;
    }
    float msum = 0.f;
#pragma unroll
    for (int l = 0; l < L_; ++l) {
      float v = s_attn[tid][l] / ssum;
      s_attn[tid][l] = v;
      if (l < len) msum += v;
    }
    float den = msum + 1e-7f;
#pragma unroll
    for (int l = 0; l < L_; ++l)
      s_attn[tid][l] = (l < len) ? s_attn[tid][l] / den : 0.f;
  }
  __syncthreads();

  // ins (PV) + combine + score
  {
    float acc[K1_];
#pragma unroll
    for (int k = 0; k < K1_; ++k) acc[k] = 0.f;
    for (int l = 0; l < L_; ++l) {
      float lv = s_lang[l][tid];
#pragma unroll
      for (int k = 0; k < K1_; ++k) acc[k] += s_attn[k][l] * lv;
    }
    float o = s_f[tid];
#pragma unroll
    for (int k = 0; k < K1_; ++k)
      o += s_fnb[k][tid] * acc[k] * s_relo[k][tid];
    out[(size_t)b * D_ + tid] = o;

    float v = o;
    for (int off = 32; off > 0; off >>= 1) v += __shfl_xor(v, off);
    if ((tid & 63) == 0) s_red[tid >> 6] = v;
    __syncthreads();
    if (tid == 0) score[b] = s_red[0] + s_red[1];
  }
}

extern "C" void kernel_launch(void* const* d_in, const int* in_sizes, int n_in,
                              void* d_out, int out_size, void* d_ws,
                              size_t ws_size, hipStream_t stream) {
  const float* feat = (const float*)d_in[0];
  const float* coord = (const float*)d_in[1];
  const float* lang_feat = (const float*)d_in[2];
  const int* lang_len = (const int*)d_in[3];
  const float* rel_w1 = (const float*)d_in[4];
  const float* rel_b1 = (const float*)d_in[5];
  const float* rel_w2 = (const float*)d_in[6];
  const float* rel_b2 = (const float*)d_in[7];
  const float* lang_w1 = (const float*)d_in[8];
  const float* lang_b1 = (const float*)d_in[9];
  const float* lang_w2 = (const float*)d_in[10];
  const float* lang_b2 = (const float*)d_in[11];
  const float* feat_w1 = (const float*)d_in[12];
  const float* feat_b1 = (const float*)d_in[13];
  const float* feat_w2 = (const float*)d_in[14];
  const float* feat_b2 = (const float*)d_in[15];

  char* ws = (char*)d_ws;
  float* lang_out = (float*)ws;                                   // 1 MB
  float* f_out = (float*)(ws + (1 << 20));                        // 8 MB
  int* idx = (int*)(ws + (1 << 20) + (8 << 20));                  // 2 MB region
  float* rel10 = (float*)(ws + (1 << 20) + (8 << 20) + (2 << 20));  // ~11 MB

  float* out = (float*)d_out;
  float* score = out + (size_t)S_ * N_ * D_;

  tar_knn_kernel<<<dim3(S_ * N_), dim3(64), 0, stream>>>(coord, idx, rel10);
  tar_lang_mlp_kernel<<<dim3(S_ * L_), dim3(128), 0, stream>>>(
      lang_feat, lang_w1, lang_b1, lang_w2, lang_b2, lang_out);
  tar_f_mlp_kernel<<<dim3(S_ * N_ / 8), dim3(128), 0, stream>>>(
      feat, feat_w1, feat_b1, feat_w2, feat_b2, f_out);
  tar_main_kernel<<<dim3(S_ * N_), dim3(128), 0, stream>>>(
      f_out, lang_out, idx, rel10, rel_w1, rel_b1, rel_w2, rel_b2, lang_len,
      out, score);
}

// Round 3
// 330.094 us; speedup vs baseline: 2.3838x; 2.3838x over previous
//
#include <hip/hip_runtime.h>
#include <math.h>

#define S_ 64
#define N_ 256
#define L_ 32
#define D_ 128
#define LID_ 256
#define K1_ 17
#define CH_ 32    // objects per main block
#define TILES_ 34 // CH_*K1_/16
#define NW_ 8     // waves per main block

typedef __attribute__((ext_vector_type(8))) short short8;
typedef __attribute__((ext_vector_type(4))) float f32x4;

__device__ __forceinline__ unsigned short f2bf(float f) {
  unsigned int u = __float_as_uint(f);
  u += 0x7fffu + ((u >> 16) & 1u);
  return (unsigned short)(u >> 16);
}
__device__ __forceinline__ float bf2f(unsigned short h) {
  return __uint_as_float(((unsigned int)h) << 16);
}
// wave-level LDS fence: drain DS ops, then pin scheduler (rule #18 insurance)
#define LDS_FENCE()                                   \
  do {                                                \
    asm volatile("s_waitcnt lgkmcnt(0)" ::: "memory"); \
    __builtin_amdgcn_sched_barrier(0);                \
  } while (0)

// ---------------------------------------------------------------- KNN kernel
// one wave per (s,n); lexicographic (d, idx) argmin x17 matches lax.top_k.
__global__ __launch_bounds__(64) void tar_knn_kernel(
    const float* __restrict__ coord, int* __restrict__ idx_out,
    float* __restrict__ rel10_out) {
  int b = blockIdx.x;
  int s = b >> 8;
  int n = b & 255;
  int lane = threadIdx.x;
  const float* cs = coord + (size_t)s * N_ * 3;
  float cx = cs[n * 3 + 0], cy = cs[n * 3 + 1], cz = cs[n * 3 + 2];
  float d[4];
  int jj[4];
#pragma unroll
  for (int q = 0; q < 4; ++q) {
    int j = q * 64 + lane;
    float dx = cs[j * 3 + 0] - cx;
    float dy = cs[j * 3 + 1] - cy;
    float dz = cs[j * 3 + 2] - cz;
    d[q] = dx * dx + dy * dy + dz * dz;
    jj[q] = j;
  }
  for (int k = 0; k < K1_; ++k) {
    float bd = 1e30f;
    int bj = 1 << 30;
#pragma unroll
    for (int q = 0; q < 4; ++q) {
      if (d[q] < bd || (d[q] == bd && jj[q] < bj)) { bd = d[q]; bj = jj[q]; }
    }
    for (int off = 32; off > 0; off >>= 1) {
      float od = __shfl_xor(bd, off);
      int oj = __shfl_xor(bj, off);
      if (od < bd || (od == bd && oj < bj)) { bd = od; bj = oj; }
    }
#pragma unroll
    for (int q = 0; q < 4; ++q)
      if (jj[q] == bj) d[q] = 1e30f;
    if (lane == 0) {
      idx_out[(size_t)b * K1_ + k] = bj;
      float nx = cs[bj * 3 + 0], ny = cs[bj * 3 + 1], nz = cs[bj * 3 + 2];
      float rx = nx - cx, ry = ny - cy, rz = nz - cz;
      float dist = sqrtf(rx * rx + ry * ry + rz * rz);
      float* r = rel10_out + ((size_t)b * K1_ + k) * 10;
      r[0] = nx; r[1] = ny; r[2] = nz;
      r[3] = cx; r[4] = cy; r[5] = cz;
      r[6] = rx; r[7] = ry; r[8] = rz; r[9] = dist;
    }
  }
}

// ---------------------------------------------------------------- lang MLP
// one block per (s,l) row: 256 -> relu 128 -> 128; emits bf16 + bf16-transposed
__global__ __launch_bounds__(128) void tar_lang_mlp_kernel(
    const float* __restrict__ x, const float* __restrict__ w1,
    const float* __restrict__ b1, const float* __restrict__ w2,
    const float* __restrict__ b2, unsigned short* __restrict__ y_bf,
    unsigned short* __restrict__ yT_bf) {
  __shared__ float sx[LID_];
  __shared__ float sh[D_];
  int row = blockIdx.x, j = threadIdx.x;
  const float* xr = x + (size_t)row * LID_;
  sx[j] = xr[j];
  sx[j + 128] = xr[j + 128];
  __syncthreads();
  float acc = b1[j];
#pragma unroll 8
  for (int i = 0; i < LID_; ++i) acc += sx[i] * w1[i * D_ + j];
  sh[j] = fmaxf(acc, 0.f);
  __syncthreads();
  float acc2 = b2[j];
#pragma unroll 8
  for (int h = 0; h < D_; ++h) acc2 += sh[h] * w2[h * D_ + j];
  unsigned short hb = f2bf(acc2);
  y_bf[(size_t)row * D_ + j] = hb;
  int s = row >> 5, l = row & 31;
  yT_bf[((size_t)s * D_ + j) * L_ + l] = hb;
}

// ---------------------------------------------------------------- feat MLP
// 8 rows per block: 128 -> relu 128 -> 128; emits f32 and bf16
__global__ __launch_bounds__(128) void tar_f_mlp_kernel(
    const float* __restrict__ x, const float* __restrict__ w1,
    const float* __restrict__ b1, const float* __restrict__ w2,
    const float* __restrict__ b2, float* __restrict__ y,
    unsigned short* __restrict__ y_bf) {
  __shared__ float sx[8][D_];
  __shared__ float sh[8][D_];
  int base = blockIdx.x * 8, j = threadIdx.x;
  for (int r = 0; r < 8; ++r) sx[r][j] = x[(size_t)(base + r) * D_ + j];
  __syncthreads();
  float acc[8];
  float bb = b1[j];
#pragma unroll
  for (int r = 0; r < 8; ++r) acc[r] = bb;
  for (int i = 0; i < D_; ++i) {
    float w = w1[i * D_ + j];
#pragma unroll
    for (int r = 0; r < 8; ++r) acc[r] += sx[r][i] * w;
  }
#pragma unroll
  for (int r = 0; r < 8; ++r) sh[r][j] = fmaxf(acc[r], 0.f);
  __syncthreads();
  float bb2 = b2[j];
#pragma unroll
  for (int r = 0; r < 8; ++r) acc[r] = bb2;
  for (int h = 0; h < D_; ++h) {
    float w = w2[h * D_ + j];
#pragma unroll
    for (int r = 0; r < 8; ++r) acc[r] += sh[r][h] * w;
  }
#pragma unroll
  for (int r = 0; r < 8; ++r) {
    y[(size_t)(base + r) * D_ + j] = acc[r];
    y_bf[(size_t)(base + r) * D_ + j] = f2bf(acc[r]);
  }
}

// ---------------------------------------------------------------- weight prep
// w2T[n][k] = w2[k][n] bf16 ; w1T[n][k] = (k<10)? w1[k][n] : 0, K padded to 16
__global__ __launch_bounds__(256) void tar_prep_kernel(
    const float* __restrict__ w1, const float* __restrict__ w2,
    unsigned short* __restrict__ w1T, unsigned short* __restrict__ w2T) {
  int t = blockIdx.x * 256 + threadIdx.x;
  {
    int k = t >> 7, n = t & 127;
    w2T[(size_t)n * 128 + k] = f2bf(w2[(size_t)k * 128 + n]);
  }
  if (t < 128 * 16) {
    int n = t >> 4, k = t & 15;
    w1T[(size_t)n * 16 + k] = (k < 10) ? f2bf(w1[(size_t)k * 128 + n]) : 0;
  }
}

// ---------------------------------------------------------------- main MFMA
// block = (sentence, 32 objects). 8 waves; wave owns 16-row M-tiles of the
// 544-row (32 obj x 17 nbr) panel. Per tile: QK^T -> softmax -> relMLP -> PV
// -> elementwise combine, accumulated into per-object LDS via ds atomics.
__global__ __launch_bounds__(512) void tar_main_mfma(
    const float* __restrict__ f_out, const unsigned short* __restrict__ f_bf,
    const unsigned short* __restrict__ lang_bf,
    const unsigned short* __restrict__ langT_bf, const int* __restrict__ idxg,
    const float* __restrict__ rel10g, const unsigned short* __restrict__ w1T_bf,
    const unsigned short* __restrict__ w2T_bf,
    const float* __restrict__ rel_b1, const float* __restrict__ rel_b2,
    const int* __restrict__ lang_len, float* __restrict__ outp,
    float* __restrict__ score) {
  // padded strides: 136/40/24 shorts and 132 floats -> bank-balanced b128 reads
  __shared__ unsigned short lang_s[L_ * 136];    // [32][136]
  __shared__ unsigned short langT_s[D_ * 40];    // [128][40]
  __shared__ unsigned short w2T_s[D_ * 136];     // [128][136]
  __shared__ unsigned short w1T_s[D_ * 24];      // [128][24]
  __shared__ float out_acc[CH_ * 132];           // [32][132]
  __shared__ unsigned short fnb_s[NW_][16 * 136];
  __shared__ unsigned short relh_s[NW_][16 * 136];
  __shared__ unsigned short P_s[NW_][16 * 40];

  int b = blockIdx.x;
  int s = b >> 3;
  int chunk = b & 7;
  int sn0 = s * N_ + chunk * CH_;
  int tid = threadIdx.x;
  int w = tid >> 6;
  int l = tid & 63;
  int g = l >> 4;
  int ln = l & 15;
  int len = lang_len[s];

  // ---- stage block-shared LDS
  {
    int row = tid >> 4, c0 = (tid & 15) * 8;  // lang: 32 rows x 16 chunks
    *(short8*)&lang_s[row * 136 + c0] =
        *(const short8*)&lang_bf[((size_t)s * L_ + row) * D_ + c0];
  }
  {
    int row = tid >> 2, c0 = (tid & 3) * 8;  // langT: 128 rows x 4 chunks
    *(short8*)&langT_s[row * 40 + c0] =
        *(const short8*)&langT_bf[((size_t)s * D_ + row) * L_ + c0];
  }
  {
    int row = tid >> 2, c0 = (tid & 3) * 32;  // w2T: 128 rows x 4 x 32
#pragma unroll
    for (int i = 0; i < 4; ++i)
      *(short8*)&w2T_s[row * 136 + c0 + i * 8] =
          *(const short8*)&w2T_bf[(size_t)row * 128 + c0 + i * 8];
  }
  if (tid < 256) {
    int row = tid >> 1, c0 = (tid & 1) * 8;  // w1T: 128 rows x 2 chunks
    *(short8*)&w1T_s[row * 24 + c0] =
        *(const short8*)&w1T_bf[(size_t)row * 16 + c0];
  }
  {
    int obj = tid >> 4, c0 = (tid & 15) * 8;  // out_acc init = f
    const float4* src = (const float4*)&f_out[((size_t)(sn0 + obj)) * D_ + c0];
    *(float4*)&out_acc[obj * 132 + c0] = src[0];
    *(float4*)&out_acc[obj * 132 + c0 + 4] = src[1];
  }
  __syncthreads();

  float b1v[8], b2v[8];
#pragma unroll
  for (int nt = 0; nt < 8; ++nt) {
    b1v[nt] = rel_b1[nt * 16 + ln];
    b2v[nt] = rel_b2[nt * 16 + ln];
  }

  unsigned short* fnb = fnb_s[w];
  unsigned short* relh = relh_s[w];
  unsigned short* P = P_s[w];

  for (int mt = w; mt < TILES_; mt += NW_) {
    int R0 = mt * 16;
    LDS_FENCE();  // WAR: previous tile's reads complete before restaging
    // ---- stage f_nb tile: lane covers row l>>2, 32-col chunk (l&3)*32
    {
      int lr = l >> 2, c0 = (l & 3) * 32;
      int gr = R0 + lr;
      int obj = ((unsigned)gr * 241u) >> 12;  // gr/17, exact in range
      int kk = gr - obj * 17;
      int nbr = idxg[(size_t)(sn0 + obj) * K1_ + kk];
      // nbr is a WITHIN-SENTENCE index -> add sentence base (round-2 bugfix)
      const short8* src =
          (const short8*)&f_bf[((size_t)s * N_ + nbr) * D_ + c0];
      short8* dst = (short8*)&fnb[lr * 136 + c0];
#pragma unroll
      for (int i = 0; i < 4; ++i) dst[i] = src[i];
    }
    LDS_FENCE();  // staging visible to all lanes of this wave

    // ---- G3: attn = f_nb @ lang^T   (M=16, N=32, K=128)
    f32x4 at0 = {0.f, 0.f, 0.f, 0.f}, at1 = {0.f, 0.f, 0.f, 0.f};
#pragma unroll
    for (int kk = 0; kk < 4; ++kk) {
      short8 a = *(const short8*)&fnb[ln * 136 + kk * 32 + g * 8];
      short8 bb0 = *(const short8*)&lang_s[(0 * 16 + ln) * 136 + kk * 32 + g * 8];
      short8 bb1 = *(const short8*)&lang_s[(1 * 16 + ln) * 136 + kk * 32 + g * 8];
      at0 = __builtin_amdgcn_mfma_f32_16x16x32_bf16(a, bb0, at0, 0, 0, 0);
      at1 = __builtin_amdgcn_mfma_f32_16x16x32_bf16(a, bb1, at1, 0, 0, 0);
    }
    // ---- softmax (ref-exact: softmax over 32, mask, renorm +1e-7)
    // D layout: value (row=g*4+reg, token=half*16+ln); reduce over ln.
#pragma unroll
    for (int reg = 0; reg < 4; ++reg) {
      float v0 = at0[reg], v1 = at1[reg];
      float mx = fmaxf(v0, v1);
      mx = fmaxf(mx, __shfl_xor(mx, 1));
      mx = fmaxf(mx, __shfl_xor(mx, 2));
      mx = fmaxf(mx, __shfl_xor(mx, 4));
      mx = fmaxf(mx, __shfl_xor(mx, 8));
      float e0 = expf(v0 - mx), e1 = expf(v1 - mx);
      float ss = e0 + e1;
      ss += __shfl_xor(ss, 1);
      ss += __shfl_xor(ss, 2);
      ss += __shfl_xor(ss, 4);
      ss += __shfl_xor(ss, 8);
      float q0 = (ln < len) ? e0 : 0.f;
      float q1 = (16 + ln < len) ? e1 : 0.f;
      float ms = q0 + q1;
      ms += __shfl_xor(ms, 1);
      ms += __shfl_xor(ms, 2);
      ms += __shfl_xor(ms, 4);
      ms += __shfl_xor(ms, 8);
      // q/ssum / (ms/ssum + 1e-7) == q / (ms + 1e-7*ssum)
      float inv = 1.0f / (ms + 1e-7f * ss);
      int row = g * 4 + reg;
      P[row * 40 + ln] = f2bf(q0 * inv);
      P[row * 40 + 16 + ln] = f2bf(q1 * inv);
    }

    // ---- G1: relh = relu(rel10 @ w1 + b1)  (K padded 10->32)
    short8 a1v = {0, 0, 0, 0, 0, 0, 0, 0};
    {
      int gr = R0 + ln;
      int obj = ((unsigned)gr * 241u) >> 12;
      int kk10 = gr - obj * 17;
      const float* r10 = &rel10g[((size_t)(sn0 + obj) * K1_ + kk10) * 10];
      if (g == 0) {
        float2 p0 = *(const float2*)(r10 + 0);
        float2 p1 = *(const float2*)(r10 + 2);
        float2 p2 = *(const float2*)(r10 + 4);
        float2 p3 = *(const float2*)(r10 + 6);
        a1v[0] = (short)f2bf(p0.x); a1v[1] = (short)f2bf(p0.y);
        a1v[2] = (short)f2bf(p1.x); a1v[3] = (short)f2bf(p1.y);
        a1v[4] = (short)f2bf(p2.x); a1v[5] = (short)f2bf(p2.y);
        a1v[6] = (short)f2bf(p3.x); a1v[7] = (short)f2bf(p3.y);
      } else if (g == 1) {
        float2 p4 = *(const float2*)(r10 + 8);
        a1v[0] = (short)f2bf(p4.x); a1v[1] = (short)f2bf(p4.y);
      }
    }
    f32x4 rh[8];
#pragma unroll
    for (int nt = 0; nt < 8; ++nt) {
      f32x4 acc = {b1v[nt], b1v[nt], b1v[nt], b1v[nt]};
      short8 bw = {0, 0, 0, 0, 0, 0, 0, 0};
      if (g < 2) bw = *(const short8*)&w1T_s[(nt * 16 + ln) * 24 + g * 8];
      rh[nt] = __builtin_amdgcn_mfma_f32_16x16x32_bf16(a1v, bw, acc, 0, 0, 0);
    }
#pragma unroll
    for (int nt = 0; nt < 8; ++nt)
#pragma unroll
      for (int reg = 0; reg < 4; ++reg)
        relh[(g * 4 + reg) * 136 + nt * 16 + ln] =
            f2bf(fmaxf(rh[nt][reg], 0.f));
    LDS_FENCE();  // P + relh visible

    // ---- G2: relo = relh @ w2 + b2   (M=16, N=128, K=128)
    short8 a2[4];
#pragma unroll
    for (int kk = 0; kk < 4; ++kk)
      a2[kk] = *(const short8*)&relh[ln * 136 + kk * 32 + g * 8];
    f32x4 ro[8];
#pragma unroll
    for (int nt = 0; nt < 8; ++nt) {
      f32x4 acc = {b2v[nt], b2v[nt], b2v[nt], b2v[nt]};
#pragma unroll
      for (int kk = 0; kk < 4; ++kk) {
        short8 bw = *(const short8*)&w2T_s[(nt * 16 + ln) * 136 + kk * 32 + g * 8];
        acc = __builtin_amdgcn_mfma_f32_16x16x32_bf16(a2[kk], bw, acc, 0, 0, 0);
      }
      ro[nt] = acc;
    }

    // ---- G4: ins = P @ lang   (M=16, N=128, K=32)
    short8 pa = *(const short8*)&P[ln * 40 + g * 8];
    f32x4 insv[8];
#pragma unroll
    for (int nt = 0; nt < 8; ++nt) {
      f32x4 acc = {0.f, 0.f, 0.f, 0.f};
      short8 bw = *(const short8*)&langT_s[(nt * 16 + ln) * 40 + g * 8];
      insv[nt] = __builtin_amdgcn_mfma_f32_16x16x32_bf16(pa, bw, acc, 0, 0, 0);
    }

    // ---- combine: out_acc[obj][col] += f_nb * ins * relo
#pragma unroll
    for (int nt = 0; nt < 8; ++nt)
#pragma unroll
      for (int reg = 0; reg < 4; ++reg) {
        int row = g * 4 + reg;
        int col = nt * 16 + ln;
        float fv = bf2f(fnb[row * 136 + col]);
        float gv = fv * insv[nt][reg] * ro[nt][reg];
        int gr = R0 + row;
        int obj = ((unsigned)gr * 241u) >> 12;
        atomicAdd(&out_acc[obj * 132 + col], gv);
      }
  }
  __syncthreads();

  // ---- epilogue: write out + per-object score reduction
  {
    int obj = tid >> 4, c0 = (tid & 15) * 8;
    float4 v0 = *(float4*)&out_acc[obj * 132 + c0];
    float4 v1 = *(float4*)&out_acc[obj * 132 + c0 + 4];
    *(float4*)&outp[((size_t)(sn0 + obj)) * D_ + c0] = v0;
    *(float4*)&outp[((size_t)(sn0 + obj)) * D_ + c0 + 4] = v1;
    float sum = v0.x + v0.y + v0.z + v0.w + v1.x + v1.y + v1.z + v1.w;
    sum += __shfl_xor(sum, 1);
    sum += __shfl_xor(sum, 2);
    sum += __shfl_xor(sum, 4);
    sum += __shfl_xor(sum, 8);
    if ((tid & 15) == 0) score[sn0 + obj] = sum;
  }
}

extern "C" void kernel_launch(void* const* d_in, const int* in_sizes, int n_in,
                              void* d_out, int out_size, void* d_ws,
                              size_t ws_size, hipStream_t stream) {
  const float* feat = (const float*)d_in[0];
  const float* coord = (const float*)d_in[1];
  const float* lang_feat = (const float*)d_in[2];
  const int* lang_len = (const int*)d_in[3];
  const float* rel_w1 = (const float*)d_in[4];
  const float* rel_b1 = (const float*)d_in[5];
  const float* rel_w2 = (const float*)d_in[6];
  const float* rel_b2 = (const float*)d_in[7];
  const float* lang_w1 = (const float*)d_in[8];
  const float* lang_b1 = (const float*)d_in[9];
  const float* lang_w2 = (const float*)d_in[10];
  const float* lang_b2 = (const float*)d_in[11];
  const float* feat_w1 = (const float*)d_in[12];
  const float* feat_b1 = (const float*)d_in[13];
  const float* feat_w2 = (const float*)d_in[14];
  const float* feat_b2 = (const float*)d_in[15];

  char* ws = (char*)d_ws;
  unsigned short* lang_bf = (unsigned short*)(ws);                  // 512 KB
  unsigned short* langT_bf = (unsigned short*)(ws + 524288);        // 512 KB
  float* f_out = (float*)(ws + 1048576);                            // 8 MB
  unsigned short* f_bf = (unsigned short*)(ws + 9437184);           // 4 MB
  int* idx = (int*)(ws + 13631488);                                 // ~1.1 MB
  float* rel10 = (float*)(ws + 14745600);                           // ~11.1 MB
  unsigned short* w2T_bf = (unsigned short*)(ws + 25886720);        // 32 KB
  unsigned short* w1T_bf = (unsigned short*)(ws + 25919488);        // 4 KB

  float* out = (float*)d_out;
  float* score = out + (size_t)S_ * N_ * D_;

  tar_knn_kernel<<<dim3(S_ * N_), dim3(64), 0, stream>>>(coord, idx, rel10);
  tar_lang_mlp_kernel<<<dim3(S_ * L_), dim3(128), 0, stream>>>(
      lang_feat, lang_w1, lang_b1, lang_w2, lang_b2, lang_bf, langT_bf);
  tar_f_mlp_kernel<<<dim3(S_ * N_ / 8), dim3(128), 0, stream>>>(
      feat, feat_w1, feat_b1, feat_w2, feat_b2, f_out, f_bf);
  tar_prep_kernel<<<dim3(64), dim3(256), 0, stream>>>(rel_w1, rel_w2, w1T_bf,
                                                      w2T_bf);
  tar_main_mfma<<<dim3(S_ * (N_ / CH_)), dim3(512), 0, stream>>>(
      f_out, f_bf, lang_bf, langT_bf, idx, rel10, w1T_bf, w2T_bf, rel_b1,
      rel_b2, lang_len, out, score);
}

// Round 4
// 287.948 us; speedup vs baseline: 2.7327x; 1.1464x over previous
//
#include <hip/hip_runtime.h>
#include <math.h>

#define S_ 64
#define N_ 256
#define L_ 32
#define D_ 128
#define LID_ 256
#define K1_ 17
#define CH_ 32    // objects per main block
#define NW_ 8     // waves per main block

typedef __attribute__((ext_vector_type(8))) short short8;
typedef __attribute__((ext_vector_type(4))) float f32x4;

__device__ __forceinline__ unsigned short f2bf(float f) {
  unsigned int u = __float_as_uint(f);
  u += 0x7fffu + ((u >> 16) & 1u);
  return (unsigned short)(u >> 16);
}
__device__ __forceinline__ float bf2f(unsigned short h) {
  return __uint_as_float(((unsigned int)h) << 16);
}
// wave-level LDS fence: drain DS ops, then pin scheduler (rule #18 insurance)
#define LDS_FENCE()                                    \
  do {                                                 \
    asm volatile("s_waitcnt lgkmcnt(0)" ::: "memory"); \
    __builtin_amdgcn_sched_barrier(0);                 \
  } while (0)

// ---------------------------------------------------------------- KNN kernel
__global__ __launch_bounds__(64) void tar_knn_kernel(
    const float* __restrict__ coord, int* __restrict__ idx_out,
    float* __restrict__ rel10_out) {
  int b = blockIdx.x;
  int s = b >> 8;
  int n = b & 255;
  int lane = threadIdx.x;
  const float* cs = coord + (size_t)s * N_ * 3;
  float cx = cs[n * 3 + 0], cy = cs[n * 3 + 1], cz = cs[n * 3 + 2];
  float d[4];
  int jj[4];
#pragma unroll
  for (int q = 0; q < 4; ++q) {
    int j = q * 64 + lane;
    float dx = cs[j * 3 + 0] - cx;
    float dy = cs[j * 3 + 1] - cy;
    float dz = cs[j * 3 + 2] - cz;
    d[q] = dx * dx + dy * dy + dz * dz;
    jj[q] = j;
  }
  for (int k = 0; k < K1_; ++k) {
    float bd = 1e30f;
    int bj = 1 << 30;
#pragma unroll
    for (int q = 0; q < 4; ++q) {
      if (d[q] < bd || (d[q] == bd && jj[q] < bj)) { bd = d[q]; bj = jj[q]; }
    }
    for (int off = 32; off > 0; off >>= 1) {
      float od = __shfl_xor(bd, off);
      int oj = __shfl_xor(bj, off);
      if (od < bd || (od == bd && oj < bj)) { bd = od; bj = oj; }
    }
#pragma unroll
    for (int q = 0; q < 4; ++q)
      if (jj[q] == bj) d[q] = 1e30f;
    if (lane == 0) {
      idx_out[(size_t)b * K1_ + k] = bj;
      float nx = cs[bj * 3 + 0], ny = cs[bj * 3 + 1], nz = cs[bj * 3 + 2];
      float rx = nx - cx, ry = ny - cy, rz = nz - cz;
      float dist = sqrtf(rx * rx + ry * ry + rz * rz);
      float* r = rel10_out + ((size_t)b * K1_ + k) * 10;
      r[0] = nx; r[1] = ny; r[2] = nz;
      r[3] = cx; r[4] = cy; r[5] = cz;
      r[6] = rx; r[7] = ry; r[8] = rz; r[9] = dist;
    }
  }
}

// ---------------------------------------------------------------- lang MLP
__global__ __launch_bounds__(128) void tar_lang_mlp_kernel(
    const float* __restrict__ x, const float* __restrict__ w1,
    const float* __restrict__ b1, const float* __restrict__ w2,
    const float* __restrict__ b2, unsigned short* __restrict__ y_bf,
    unsigned short* __restrict__ yT_bf) {
  __shared__ float sx[LID_];
  __shared__ float sh[D_];
  int row = blockIdx.x, j = threadIdx.x;
  const float* xr = x + (size_t)row * LID_;
  sx[j] = xr[j];
  sx[j + 128] = xr[j + 128];
  __syncthreads();
  float acc = b1[j];
#pragma unroll 8
  for (int i = 0; i < LID_; ++i) acc += sx[i] * w1[i * D_ + j];
  sh[j] = fmaxf(acc, 0.f);
  __syncthreads();
  float acc2 = b2[j];
#pragma unroll 8
  for (int h = 0; h < D_; ++h) acc2 += sh[h] * w2[h * D_ + j];
  unsigned short hb = f2bf(acc2);
  y_bf[(size_t)row * D_ + j] = hb;
  int s = row >> 5, l = row & 31;
  yT_bf[((size_t)s * D_ + j) * L_ + l] = hb;
}

// ---------------------------------------------------------------- feat MLP
__global__ __launch_bounds__(128) void tar_f_mlp_kernel(
    const float* __restrict__ x, const float* __restrict__ w1,
    const float* __restrict__ b1, const float* __restrict__ w2,
    const float* __restrict__ b2, float* __restrict__ y,
    unsigned short* __restrict__ y_bf) {
  __shared__ float sx[8][D_];
  __shared__ float sh[8][D_];
  int base = blockIdx.x * 8, j = threadIdx.x;
  for (int r = 0; r < 8; ++r) sx[r][j] = x[(size_t)(base + r) * D_ + j];
  __syncthreads();
  float acc[8];
  float bb = b1[j];
#pragma unroll
  for (int r = 0; r < 8; ++r) acc[r] = bb;
  for (int i = 0; i < D_; ++i) {
    float w = w1[i * D_ + j];
#pragma unroll
    for (int r = 0; r < 8; ++r) acc[r] += sx[r][i] * w;
  }
#pragma unroll
  for (int r = 0; r < 8; ++r) sh[r][j] = fmaxf(acc[r], 0.f);
  __syncthreads();
  float bb2 = b2[j];
#pragma unroll
  for (int r = 0; r < 8; ++r) acc[r] = bb2;
  for (int h = 0; h < D_; ++h) {
    float w = w2[h * D_ + j];
#pragma unroll
    for (int r = 0; r < 8; ++r) acc[r] += sh[r][h] * w;
  }
#pragma unroll
  for (int r = 0; r < 8; ++r) {
    y[(size_t)(base + r) * D_ + j] = acc[r];
    y_bf[(size_t)(base + r) * D_ + j] = f2bf(acc[r]);
  }
}

// ---------------------------------------------------------------- weight prep
__global__ __launch_bounds__(256) void tar_prep_kernel(
    const float* __restrict__ w1, const float* __restrict__ w2,
    unsigned short* __restrict__ w1T, unsigned short* __restrict__ w2T) {
  int t = blockIdx.x * 256 + threadIdx.x;
  {
    int k = t >> 7, n = t & 127;
    w2T[(size_t)n * 128 + k] = f2bf(w2[(size_t)k * 128 + n]);
  }
  if (t < 128 * 16) {
    int n = t >> 4, k = t & 15;
    w1T[(size_t)n * 16 + k] = (k < 10) ? f2bf(w1[(size_t)k * 128 + n]) : 0;
  }
}

// ---------------------------------------------------------------- main MFMA
// block = (sentence, 32 objects), 8 waves. K-MAJOR tiling: a tile is
// (16 objects, one neighbor-rank k). Wave (og=w>>2, q=w&3) handles objects
// og*16..og*16+15 for k = q, q+4, ... ; k-sum accumulates in REGISTERS
// (no LDS atomics). Cross-wave (4 waves/group) reduce at the end via LDS.
// w2T + f_nb fragments come straight from global (L1/L2-hot) -> LDS 72.3KB
// -> 2 blocks/CU.
__global__ __launch_bounds__(512, 4) void tar_main_mfma(
    const float* __restrict__ f_out, const unsigned short* __restrict__ f_bf,
    const unsigned short* __restrict__ lang_bf,
    const unsigned short* __restrict__ langT_bf, const int* __restrict__ idxg,
    const float* __restrict__ rel10g, const unsigned short* __restrict__ w1T_bf,
    const unsigned short* __restrict__ w2T_bf,
    const float* __restrict__ rel_b1, const float* __restrict__ rel_b2,
    const int* __restrict__ lang_len, float* __restrict__ outp,
    float* __restrict__ score) {
  // arena layout (bytes):
  //   0      lang_s   [32][136] u16   8704
  //   8704   langT_s  [128][40] u16  10240
  //   18944  w1T_s    [128][24] u16   6144
  //   25088  relh_w   8x[16][136]u16 34816
  //   59904  P_w      8x[16][48] u16 12288   (tokens 0-15 @0, 16-31 @24)
  //   total 72192; epilogue aliases as R = f32 [8][128][16] (65536)
  __shared__ __align__(16) char arena[72192];
  __shared__ float score_s[CH_];

  unsigned short* lang_s = (unsigned short*)(arena);
  unsigned short* langT_s = (unsigned short*)(arena + 8704);
  unsigned short* w1T_s = (unsigned short*)(arena + 18944);

  int b = blockIdx.x;
  int s = b >> 3;
  int chunk = b & 7;
  int sn0 = s * N_ + chunk * CH_;
  int tid = threadIdx.x;
  int w = tid >> 6;
  int l = tid & 63;
  int g = l >> 4;
  int ln = l & 15;
  int og = w >> 2;   // object group (0/1): objects og*16 .. og*16+15
  int q = w & 3;     // k-stride lane: k = q, q+4, ...
  int len = lang_len[s];

  unsigned short* relh = (unsigned short*)(arena + 25088 + w * 4352);
  unsigned short* P = (unsigned short*)(arena + 59904 + w * 1536);

  // ---- stage block-shared LDS
  {
    int row = tid >> 4, c0 = (tid & 15) * 8;  // lang: 32 rows x 16 chunks
    *(short8*)&lang_s[row * 136 + c0] =
        *(const short8*)&lang_bf[((size_t)s * L_ + row) * D_ + c0];
  }
  {
    int row = tid >> 2, c0 = (tid & 3) * 8;  // langT: 128 rows x 4 chunks
    *(short8*)&langT_s[row * 40 + c0] =
        *(const short8*)&langT_bf[((size_t)s * D_ + row) * L_ + c0];
  }
  if (tid < 256) {
    int row = tid >> 1, c0 = (tid & 1) * 8;  // w1T: 128 rows x 2 chunks
    *(short8*)&w1T_s[row * 24 + c0] =
        *(const short8*)&w1T_bf[(size_t)row * 16 + c0];
  }
  if (tid < CH_) score_s[tid] = 0.f;
  __syncthreads();

  float b1v[8], b2v[8];
#pragma unroll
  for (int nt = 0; nt < 8; ++nt) {
    b1v[nt] = rel_b1[nt * 16 + ln];
    b2v[nt] = rel_b2[nt * 16 + ln];
  }

  f32x4 o[8];
#pragma unroll
  for (int nt = 0; nt < 8; ++nt) o[nt] = (f32x4){0.f, 0.f, 0.f, 0.f};

  int objA = og * 16 + ln;  // A-fragment row owned by this lane

  for (int k = q; k < K1_; k += 4) {
    LDS_FENCE();  // WAR: prior tile's P/relh reads done before restaging

    // ---- f_nb A-fragments straight from global (row=objA's k-th neighbor)
    int nbrA = idxg[(size_t)(sn0 + objA) * K1_ + k];
    const unsigned short* fArow = &f_bf[((size_t)s * N_ + nbrA) * D_];
    short8 fA[4];
#pragma unroll
    for (int kk = 0; kk < 4; ++kk)
      fA[kk] = *(const short8*)&fArow[kk * 32 + g * 8];

    // ---- G3: attn = f_nb @ lang^T   (M=16 objs, N=32 tokens, K=128)
    f32x4 at0 = {0.f, 0.f, 0.f, 0.f}, at1 = {0.f, 0.f, 0.f, 0.f};
#pragma unroll
    for (int kk = 0; kk < 4; ++kk) {
      short8 bb0 = *(const short8*)&lang_s[ln * 136 + kk * 32 + g * 8];
      short8 bb1 = *(const short8*)&lang_s[(16 + ln) * 136 + kk * 32 + g * 8];
      at0 = __builtin_amdgcn_mfma_f32_16x16x32_bf16(fA[kk], bb0, at0, 0, 0, 0);
      at1 = __builtin_amdgcn_mfma_f32_16x16x32_bf16(fA[kk], bb1, at1, 0, 0, 0);
    }
    // ---- softmax (ref-exact: softmax over 32, mask, renorm +1e-7)
    // C layout: (row=g*4+reg -> obj, col=half*16+ln -> token); reduce over ln.
#pragma unroll
    for (int reg = 0; reg < 4; ++reg) {
      float v0 = at0[reg], v1 = at1[reg];
      float mx = fmaxf(v0, v1);
      mx = fmaxf(mx, __shfl_xor(mx, 1));
      mx = fmaxf(mx, __shfl_xor(mx, 2));
      mx = fmaxf(mx, __shfl_xor(mx, 4));
      mx = fmaxf(mx, __shfl_xor(mx, 8));
      float e0 = expf(v0 - mx), e1 = expf(v1 - mx);
      float ss = e0 + e1;
      ss += __shfl_xor(ss, 1);
      ss += __shfl_xor(ss, 2);
      ss += __shfl_xor(ss, 4);
      ss += __shfl_xor(ss, 8);
      float q0 = (ln < len) ? e0 : 0.f;
      float q1 = (16 + ln < len) ? e1 : 0.f;
      float ms = q0 + q1;
      ms += __shfl_xor(ms, 1);
      ms += __shfl_xor(ms, 2);
      ms += __shfl_xor(ms, 4);
      ms += __shfl_xor(ms, 8);
      float inv = 1.0f / (ms + 1e-7f * ss);  // == ref algebra exactly
      int row = g * 4 + reg;
      P[row * 48 + ln] = f2bf(q0 * inv);
      P[row * 48 + 24 + ln] = f2bf(q1 * inv);
    }

    // ---- G1: relh = relu(rel10 @ w1 + b1)  (K padded 10->32)
    short8 a1v = {0, 0, 0, 0, 0, 0, 0, 0};
    {
      const float* r10 = &rel10g[((size_t)(sn0 + objA) * K1_ + k) * 10];
      if (g == 0) {
        float2 p0 = *(const float2*)(r10 + 0);
        float2 p1 = *(const float2*)(r10 + 2);
        float2 p2 = *(const float2*)(r10 + 4);
        float2 p3 = *(const float2*)(r10 + 6);
        a1v[0] = (short)f2bf(p0.x); a1v[1] = (short)f2bf(p0.y);
        a1v[2] = (short)f2bf(p1.x); a1v[3] = (short)f2bf(p1.y);
        a1v[4] = (short)f2bf(p2.x); a1v[5] = (short)f2bf(p2.y);
        a1v[6] = (short)f2bf(p3.x); a1v[7] = (short)f2bf(p3.y);
      } else if (g == 1) {
        float2 p4 = *(const float2*)(r10 + 8);
        a1v[0] = (short)f2bf(p4.x); a1v[1] = (short)f2bf(p4.y);
      }
    }
#pragma unroll
    for (int nt = 0; nt < 8; ++nt) {
      f32x4 acc = {b1v[nt], b1v[nt], b1v[nt], b1v[nt]};
      short8 bw = {0, 0, 0, 0, 0, 0, 0, 0};
      if (g < 2) bw = *(const short8*)&w1T_s[(nt * 16 + ln) * 24 + g * 8];
      acc = __builtin_amdgcn_mfma_f32_16x16x32_bf16(a1v, bw, acc, 0, 0, 0);
#pragma unroll
      for (int reg = 0; reg < 4; ++reg)
        relh[(g * 4 + reg) * 136 + nt * 16 + ln] = f2bf(fmaxf(acc[reg], 0.f));
    }

    // ---- prefetch f_nb values needed by the combine (C layout, f32, L2-hot)
    int nbrC[4];
#pragma unroll
    for (int reg = 0; reg < 4; ++reg)
      nbrC[reg] = idxg[(size_t)(sn0 + og * 16 + g * 4 + reg) * K1_ + k];
    float fC[8][4];
#pragma unroll
    for (int nt = 0; nt < 8; ++nt)
#pragma unroll
      for (int reg = 0; reg < 4; ++reg)
        fC[nt][reg] =
            f_out[((size_t)s * N_ + nbrC[reg]) * D_ + nt * 16 + ln];

    LDS_FENCE();  // P + relh visible to all lanes of this wave

    // ---- per-nt fused: G2 (relh@w2T) + G4 (P@langT) + register combine
    short8 a2[4];
#pragma unroll
    for (int kk = 0; kk < 4; ++kk)
      a2[kk] = *(const short8*)&relh[ln * 136 + kk * 32 + g * 8];
    short8 pa = *(const short8*)&P[ln * 48 + (g >> 1) * 24 + (g & 1) * 8];
#pragma unroll
    for (int nt = 0; nt < 8; ++nt) {
      f32x4 ro = {b2v[nt], b2v[nt], b2v[nt], b2v[nt]};
#pragma unroll
      for (int kk = 0; kk < 4; ++kk) {
        short8 bw =
            *(const short8*)&w2T_bf[(size_t)(nt * 16 + ln) * 128 + kk * 32 + g * 8];
        ro = __builtin_amdgcn_mfma_f32_16x16x32_bf16(a2[kk], bw, ro, 0, 0, 0);
      }
      f32x4 iv = {0.f, 0.f, 0.f, 0.f};
      short8 bl = *(const short8*)&langT_s[(nt * 16 + ln) * 40 + g * 8];
      iv = __builtin_amdgcn_mfma_f32_16x16x32_bf16(pa, bl, iv, 0, 0, 0);
#pragma unroll
      for (int reg = 0; reg < 4; ++reg)
        o[nt][reg] += fC[nt][reg] * iv[reg] * ro[reg];
    }
  }

  // ---- cross-wave reduction (4 waves per object group) ----
  __syncthreads();  // all tile work done; arena free for reuse
  float* R = (float*)arena;  // [8 waves][128 cols][16 rows] f32
  {
    float* Rw = R + w * 2048;
#pragma unroll
    for (int nt = 0; nt < 8; ++nt)
      *(f32x4*)&Rw[(nt * 16 + ln) * 16 + g * 4] = o[nt];
  }
  __syncthreads();
  {
    float vs[2][4];
#pragma unroll
    for (int t = 0; t < 2; ++t) {
      int nt = q * 2 + t;
      int col = nt * 16 + ln;
      f32x4 sum = {0.f, 0.f, 0.f, 0.f};
#pragma unroll
      for (int w2 = 0; w2 < 4; ++w2) {
        f32x4 p = *(f32x4*)&R[(og * 4 + w2) * 2048 + col * 16 + g * 4];
        sum += p;
      }
#pragma unroll
      for (int reg = 0; reg < 4; ++reg) {
        int obj = og * 16 + g * 4 + reg;
        float v = sum[reg] + f_out[(size_t)(sn0 + obj) * D_ + col];
        outp[(size_t)(sn0 + obj) * D_ + col] = v;
        vs[t][reg] = v;
      }
    }
#pragma unroll
    for (int reg = 0; reg < 4; ++reg) {
      float sv = vs[0][reg] + vs[1][reg];
      sv += __shfl_xor(sv, 1);
      sv += __shfl_xor(sv, 2);
      sv += __shfl_xor(sv, 4);
      sv += __shfl_xor(sv, 8);
      if (ln == 0) atomicAdd(&score_s[og * 16 + g * 4 + reg], sv);
    }
  }
  __syncthreads();
  if (tid < CH_) score[sn0 + tid] = score_s[tid];
}

extern "C" void kernel_launch(void* const* d_in, const int* in_sizes, int n_in,
                              void* d_out, int out_size, void* d_ws,
                              size_t ws_size, hipStream_t stream) {
  const float* feat = (const float*)d_in[0];
  const float* coord = (const float*)d_in[1];
  const float* lang_feat = (const float*)d_in[2];
  const int* lang_len = (const int*)d_in[3];
  const float* rel_w1 = (const float*)d_in[4];
  const float* rel_b1 = (const float*)d_in[5];
  const float* rel_w2 = (const float*)d_in[6];
  const float* rel_b2 = (const float*)d_in[7];
  const float* lang_w1 = (const float*)d_in[8];
  const float* lang_b1 = (const float*)d_in[9];
  const float* lang_w2 = (const float*)d_in[10];
  const float* lang_b2 = (const float*)d_in[11];
  const float* feat_w1 = (const float*)d_in[12];
  const float* feat_b1 = (const float*)d_in[13];
  const float* feat_w2 = (const float*)d_in[14];
  const float* feat_b2 = (const float*)d_in[15];

  char* ws = (char*)d_ws;
  unsigned short* lang_bf = (unsigned short*)(ws);                  // 512 KB
  unsigned short* langT_bf = (unsigned short*)(ws + 524288);        // 512 KB
  float* f_out = (float*)(ws + 1048576);                            // 8 MB
  unsigned short* f_bf = (unsigned short*)(ws + 9437184);           // 4 MB
  int* idx = (int*)(ws + 13631488);                                 // ~1.1 MB
  float* rel10 = (float*)(ws + 14745600);                           // ~11.1 MB
  unsigned short* w2T_bf = (unsigned short*)(ws + 25886720);        // 32 KB
  unsigned short* w1T_bf = (unsigned short*)(ws + 25919488);        // 4 KB

  float* out = (float*)d_out;
  float* score = out + (size_t)S_ * N_ * D_;

  tar_knn_kernel<<<dim3(S_ * N_), dim3(64), 0, stream>>>(coord, idx, rel10);
  tar_lang_mlp_kernel<<<dim3(S_ * L_), dim3(128), 0, stream>>>(
      lang_feat, lang_w1, lang_b1, lang_w2, lang_b2, lang_bf, langT_bf);
  tar_f_mlp_kernel<<<dim3(S_ * N_ / 8), dim3(128), 0, stream>>>(
      feat, feat_w1, feat_b1, feat_w2, feat_b2, f_out, f_bf);
  tar_prep_kernel<<<dim3(64), dim3(256), 0, stream>>>(rel_w1, rel_w2, w1T_bf,
                                                      w2T_bf);
  tar_main_mfma<<<dim3(S_ * (N_ / CH_)), dim3(512), 0, stream>>>(
      f_out, f_bf, lang_bf, langT_bf, idx, rel10, w1T_bf, w2T_bf, rel_b1,
      rel_b2, lang_len, out, score);
}

// Round 5
// 277.113 us; speedup vs baseline: 2.8395x; 1.0391x over previous
//
#include <hip/hip_runtime.h>
#include <math.h>

#define S_ 64
#define N_ 256
#define L_ 32
#define D_ 128
#define LID_ 256
#define K1_ 17
#define CH_ 32    // objects per main block
#define NW_ 8     // waves per main block

typedef __attribute__((ext_vector_type(8))) short short8;
typedef __attribute__((ext_vector_type(4))) float f32x4;

__device__ __forceinline__ unsigned short f2bf(float f) {
  unsigned int u = __float_as_uint(f);
  u += 0x7fffu + ((u >> 16) & 1u);
  return (unsigned short)(u >> 16);
}
__device__ __forceinline__ float bf2f(unsigned short h) {
  return __uint_as_float(((unsigned int)h) << 16);
}
// wave-level LDS fence: drain DS ops, then pin scheduler (rule #18 insurance)
#define LDS_FENCE()                                    \
  do {                                                 \
    asm volatile("s_waitcnt lgkmcnt(0)" ::: "memory"); \
    __builtin_amdgcn_sched_barrier(0);                 \
  } while (0)

// ---------------------------------------------------------------- KNN kernel
__global__ __launch_bounds__(64) void tar_knn_kernel(
    const float* __restrict__ coord, int* __restrict__ idx_out,
    float* __restrict__ rel10_out) {
  int b = blockIdx.x;
  int s = b >> 8;
  int n = b & 255;
  int lane = threadIdx.x;
  const float* cs = coord + (size_t)s * N_ * 3;
  float cx = cs[n * 3 + 0], cy = cs[n * 3 + 1], cz = cs[n * 3 + 2];
  float d[4];
  int jj[4];
#pragma unroll
  for (int q = 0; q < 4; ++q) {
    int j = q * 64 + lane;
    float dx = cs[j * 3 + 0] - cx;
    float dy = cs[j * 3 + 1] - cy;
    float dz = cs[j * 3 + 2] - cz;
    d[q] = dx * dx + dy * dy + dz * dz;
    jj[q] = j;
  }
  for (int k = 0; k < K1_; ++k) {
    float bd = 1e30f;
    int bj = 1 << 30;
#pragma unroll
    for (int q = 0; q < 4; ++q) {
      if (d[q] < bd || (d[q] == bd && jj[q] < bj)) { bd = d[q]; bj = jj[q]; }
    }
    for (int off = 32; off > 0; off >>= 1) {
      float od = __shfl_xor(bd, off);
      int oj = __shfl_xor(bj, off);
      if (od < bd || (od == bd && oj < bj)) { bd = od; bj = oj; }
    }
#pragma unroll
    for (int q = 0; q < 4; ++q)
      if (jj[q] == bj) d[q] = 1e30f;
    if (lane == 0) {
      idx_out[(size_t)b * K1_ + k] = bj;
      float nx = cs[bj * 3 + 0], ny = cs[bj * 3 + 1], nz = cs[bj * 3 + 2];
      float rx = nx - cx, ry = ny - cy, rz = nz - cz;
      float dist = sqrtf(rx * rx + ry * ry + rz * rz);
      float* r = rel10_out + ((size_t)b * K1_ + k) * 10;
      r[0] = nx; r[1] = ny; r[2] = nz;
      r[3] = cx; r[4] = cy; r[5] = cz;
      r[6] = rx; r[7] = ry; r[8] = rz; r[9] = dist;
    }
  }
}

// ---------------------------------------------------------------- lang MLP
__global__ __launch_bounds__(128) void tar_lang_mlp_kernel(
    const float* __restrict__ x, const float* __restrict__ w1,
    const float* __restrict__ b1, const float* __restrict__ w2,
    const float* __restrict__ b2, unsigned short* __restrict__ y_bf,
    unsigned short* __restrict__ yT_bf) {
  __shared__ float sx[LID_];
  __shared__ float sh[D_];
  int row = blockIdx.x, j = threadIdx.x;
  const float* xr = x + (size_t)row * LID_;
  sx[j] = xr[j];
  sx[j + 128] = xr[j + 128];
  __syncthreads();
  float acc = b1[j];
#pragma unroll 8
  for (int i = 0; i < LID_; ++i) acc += sx[i] * w1[i * D_ + j];
  sh[j] = fmaxf(acc, 0.f);
  __syncthreads();
  float acc2 = b2[j];
#pragma unroll 8
  for (int h = 0; h < D_; ++h) acc2 += sh[h] * w2[h * D_ + j];
  unsigned short hb = f2bf(acc2);
  y_bf[(size_t)row * D_ + j] = hb;
  int s = row >> 5, l = row & 31;
  yT_bf[((size_t)s * D_ + j) * L_ + l] = hb;
}

// ---------------------------------------------------------------- weight prep
// transposed bf16 copies: rel w1 (K padded 10->16), rel w2, feat w1, feat w2
__global__ __launch_bounds__(256) void tar_prep_kernel(
    const float* __restrict__ rw1, const float* __restrict__ rw2,
    const float* __restrict__ fw1, const float* __restrict__ fw2,
    unsigned short* __restrict__ w1T, unsigned short* __restrict__ w2T,
    unsigned short* __restrict__ fw1T, unsigned short* __restrict__ fw2T) {
  int t = blockIdx.x * 256 + threadIdx.x;  // 0..16383
  int k = t >> 7, n = t & 127;
  w2T[(size_t)n * 128 + k] = f2bf(rw2[(size_t)k * 128 + n]);
  fw1T[(size_t)n * 128 + k] = f2bf(fw1[(size_t)k * 128 + n]);
  fw2T[(size_t)n * 128 + k] = f2bf(fw2[(size_t)k * 128 + n]);
  if (t < 128 * 16) {
    int n2 = t >> 4, k2 = t & 15;
    w1T[(size_t)n2 * 16 + k2] = (k2 < 10) ? f2bf(rw1[(size_t)k2 * 128 + n2]) : 0;
  }
}

// ---------------------------------------------------------------- feat MLP (MFMA)
// 64 rows per block, 4 waves x 16-row tiles; weights (transposed bf16) from
// global (L2-hot); x and hidden staged in LDS (padded stride 136).
__global__ __launch_bounds__(256) void tar_f_mlp_mfma(
    const float* __restrict__ x, const unsigned short* __restrict__ fw1T,
    const float* __restrict__ b1, const unsigned short* __restrict__ fw2T,
    const float* __restrict__ b2, float* __restrict__ y,
    unsigned short* __restrict__ y_bf) {
  __shared__ unsigned short x_s[64 * 136];
  __shared__ unsigned short h_s[4][16 * 136];
  int base = blockIdx.x * 64;
  int tid = threadIdx.x;
  int w = tid >> 6, l = tid & 63, g = l >> 4, ln = l & 15;

  for (int i = tid; i < 64 * 32; i += 256) {  // 4-col groups
    int row = i >> 5, c4 = (i & 31) * 4;
    float4 v = *(const float4*)&x[(size_t)(base + row) * D_ + c4];
    unsigned short* dst = &x_s[row * 136 + c4];
    dst[0] = f2bf(v.x); dst[1] = f2bf(v.y);
    dst[2] = f2bf(v.z); dst[3] = f2bf(v.w);
  }
  __syncthreads();

  float b1v[8], b2v[8];
#pragma unroll
  for (int nt = 0; nt < 8; ++nt) {
    b1v[nt] = b1[nt * 16 + ln];
    b2v[nt] = b2[nt * 16 + ln];
  }

  // layer 1
  short8 a1[4];
#pragma unroll
  for (int kk = 0; kk < 4; ++kk)
    a1[kk] = *(const short8*)&x_s[(w * 16 + ln) * 136 + kk * 32 + g * 8];
  unsigned short* hw = h_s[w];
#pragma unroll
  for (int nt = 0; nt < 8; ++nt) {
    f32x4 acc = {b1v[nt], b1v[nt], b1v[nt], b1v[nt]};
#pragma unroll
    for (int kk = 0; kk < 4; ++kk) {
      short8 bw =
          *(const short8*)&fw1T[(size_t)(nt * 16 + ln) * 128 + kk * 32 + g * 8];
      acc = __builtin_amdgcn_mfma_f32_16x16x32_bf16(a1[kk], bw, acc, 0, 0, 0);
    }
#pragma unroll
    for (int reg = 0; reg < 4; ++reg)
      hw[(g * 4 + reg) * 136 + nt * 16 + ln] = f2bf(fmaxf(acc[reg], 0.f));
  }
  LDS_FENCE();  // per-wave buffer, wave-synchronous

  // layer 2
  short8 a2[4];
#pragma unroll
  for (int kk = 0; kk < 4; ++kk)
    a2[kk] = *(const short8*)&hw[ln * 136 + kk * 32 + g * 8];
#pragma unroll
  for (int nt = 0; nt < 8; ++nt) {
    f32x4 acc = {b2v[nt], b2v[nt], b2v[nt], b2v[nt]};
#pragma unroll
    for (int kk = 0; kk < 4; ++kk) {
      short8 bw =
          *(const short8*)&fw2T[(size_t)(nt * 16 + ln) * 128 + kk * 32 + g * 8];
      acc = __builtin_amdgcn_mfma_f32_16x16x32_bf16(a2[kk], bw, acc, 0, 0, 0);
    }
#pragma unroll
    for (int reg = 0; reg < 4; ++reg) {
      int row = base + w * 16 + g * 4 + reg;
      int col = nt * 16 + ln;
      y[(size_t)row * D_ + col] = acc[reg];
      y_bf[(size_t)row * D_ + col] = f2bf(acc[reg]);
    }
  }
}

// ---------------------------------------------------------------- main MFMA
// block = (sentence, 32 objects), 8 waves, k-major tiling; k-sum in registers;
// cross-wave LDS reduce at the end. waves_per_eu pinned to 4 (LDS caps at
// 2 blocks/CU anyway) so the allocator gets 128 VGPRs -> no scratch spills.
__attribute__((amdgpu_waves_per_eu(4, 4))) __global__
__launch_bounds__(512) void tar_main_mfma(
    const float* __restrict__ f_out, const unsigned short* __restrict__ f_bf,
    const unsigned short* __restrict__ lang_bf,
    const unsigned short* __restrict__ langT_bf, const int* __restrict__ idxg,
    const float* __restrict__ rel10g, const unsigned short* __restrict__ w1T_bf,
    const unsigned short* __restrict__ w2T_bf,
    const float* __restrict__ rel_b1, const float* __restrict__ rel_b2,
    const int* __restrict__ lang_len, float* __restrict__ outp,
    float* __restrict__ score) {
  // arena: lang_s [32][136]u16 @0 (8704) | langT_s [128][40]u16 @8704 (10240)
  //        w1T_s [128][24]u16 @18944 (6144) | relh 8x[16][136]u16 @25088
  //        P 8x[16][48]u16 @59904 (12288) -> 72192 B total;
  //        epilogue aliases arena as R = f32 [8][128][16] (65536 B)
  __shared__ __align__(16) char arena[72192];
  __shared__ float score_s[CH_];

  unsigned short* lang_s = (unsigned short*)(arena);
  unsigned short* langT_s = (unsigned short*)(arena + 8704);
  unsigned short* w1T_s = (unsigned short*)(arena + 18944);

  int b = blockIdx.x;
  int s = b >> 3;
  int chunk = b & 7;
  int sn0 = s * N_ + chunk * CH_;
  int tid = threadIdx.x;
  int w = tid >> 6;
  int l = tid & 63;
  int g = l >> 4;
  int ln = l & 15;
  int og = w >> 2;   // object group (0/1)
  int q = w & 3;     // k-stride lane: k = q, q+4, ...
  int len = lang_len[s];

  unsigned short* relh = (unsigned short*)(arena + 25088 + w * 4352);
  unsigned short* P = (unsigned short*)(arena + 59904 + w * 1536);

  {
    int row = tid >> 4, c0 = (tid & 15) * 8;
    *(short8*)&lang_s[row * 136 + c0] =
        *(const short8*)&lang_bf[((size_t)s * L_ + row) * D_ + c0];
  }
  {
    int row = tid >> 2, c0 = (tid & 3) * 8;
    *(short8*)&langT_s[row * 40 + c0] =
        *(const short8*)&langT_bf[((size_t)s * D_ + row) * L_ + c0];
  }
  if (tid < 256) {
    int row = tid >> 1, c0 = (tid & 1) * 8;
    *(short8*)&w1T_s[row * 24 + c0] =
        *(const short8*)&w1T_bf[(size_t)row * 16 + c0];
  }
  if (tid < CH_) score_s[tid] = 0.f;
  __syncthreads();

  float b1v[8], b2v[8];
#pragma unroll
  for (int nt = 0; nt < 8; ++nt) {
    b1v[nt] = rel_b1[nt * 16 + ln];
    b2v[nt] = rel_b2[nt * 16 + ln];
  }

  f32x4 o[8];
#pragma unroll
  for (int nt = 0; nt < 8; ++nt) o[nt] = (f32x4){0.f, 0.f, 0.f, 0.f};

  int objA = og * 16 + ln;
  const float* fbase = &f_out[(size_t)s * N_ * D_];

  for (int k = q; k < K1_; k += 4) {
    LDS_FENCE();  // WAR: prior tile's P/relh reads done before restaging

    int nbrA = idxg[(size_t)(sn0 + objA) * K1_ + k];
    const unsigned short* fArow = &f_bf[((size_t)s * N_ + nbrA) * D_];
    short8 fA[4];
#pragma unroll
    for (int kk = 0; kk < 4; ++kk)
      fA[kk] = *(const short8*)&fArow[kk * 32 + g * 8];

    // ---- G3: attn = f_nb @ lang^T
    f32x4 at0 = {0.f, 0.f, 0.f, 0.f}, at1 = {0.f, 0.f, 0.f, 0.f};
#pragma unroll
    for (int kk = 0; kk < 4; ++kk) {
      short8 bb0 = *(const short8*)&lang_s[ln * 136 + kk * 32 + g * 8];
      short8 bb1 = *(const short8*)&lang_s[(16 + ln) * 136 + kk * 32 + g * 8];
      at0 = __builtin_amdgcn_mfma_f32_16x16x32_bf16(fA[kk], bb0, at0, 0, 0, 0);
      at1 = __builtin_amdgcn_mfma_f32_16x16x32_bf16(fA[kk], bb1, at1, 0, 0, 0);
    }
    // ---- softmax (ref-exact)
#pragma unroll
    for (int reg = 0; reg < 4; ++reg) {
      float v0 = at0[reg], v1 = at1[reg];
      float mx = fmaxf(v0, v1);
      mx = fmaxf(mx, __shfl_xor(mx, 1));
      mx = fmaxf(mx, __shfl_xor(mx, 2));
      mx = fmaxf(mx, __shfl_xor(mx, 4));
      mx = fmaxf(mx, __shfl_xor(mx, 8));
      float e0 = expf(v0 - mx), e1 = expf(v1 - mx);
      float ss = e0 + e1;
      ss += __shfl_xor(ss, 1);
      ss += __shfl_xor(ss, 2);
      ss += __shfl_xor(ss, 4);
      ss += __shfl_xor(ss, 8);
      float q0 = (ln < len) ? e0 : 0.f;
      float q1 = (16 + ln < len) ? e1 : 0.f;
      float ms = q0 + q1;
      ms += __shfl_xor(ms, 1);
      ms += __shfl_xor(ms, 2);
      ms += __shfl_xor(ms, 4);
      ms += __shfl_xor(ms, 8);
      float inv = 1.0f / (ms + 1e-7f * ss);
      int row = g * 4 + reg;
      P[row * 48 + ln] = f2bf(q0 * inv);
      P[row * 48 + 24 + ln] = f2bf(q1 * inv);
    }

    // ---- G1: relh = relu(rel10 @ w1 + b1)
    short8 a1v = {0, 0, 0, 0, 0, 0, 0, 0};
    {
      const float* r10 = &rel10g[((size_t)(sn0 + objA) * K1_ + k) * 10];
      if (g == 0) {
        float2 p0 = *(const float2*)(r10 + 0);
        float2 p1 = *(const float2*)(r10 + 2);
        float2 p2 = *(const float2*)(r10 + 4);
        float2 p3 = *(const float2*)(r10 + 6);
        a1v[0] = (short)f2bf(p0.x); a1v[1] = (short)f2bf(p0.y);
        a1v[2] = (short)f2bf(p1.x); a1v[3] = (short)f2bf(p1.y);
        a1v[4] = (short)f2bf(p2.x); a1v[5] = (short)f2bf(p2.y);
        a1v[6] = (short)f2bf(p3.x); a1v[7] = (short)f2bf(p3.y);
      } else if (g == 1) {
        float2 p4 = *(const float2*)(r10 + 8);
        a1v[0] = (short)f2bf(p4.x); a1v[1] = (short)f2bf(p4.y);
      }
    }
#pragma unroll
    for (int nt = 0; nt < 8; ++nt) {
      f32x4 acc = {b1v[nt], b1v[nt], b1v[nt], b1v[nt]};
      short8 bw = {0, 0, 0, 0, 0, 0, 0, 0};
      if (g < 2) bw = *(const short8*)&w1T_s[(nt * 16 + ln) * 24 + g * 8];
      acc = __builtin_amdgcn_mfma_f32_16x16x32_bf16(a1v, bw, acc, 0, 0, 0);
#pragma unroll
      for (int reg = 0; reg < 4; ++reg)
        relh[(g * 4 + reg) * 136 + nt * 16 + ln] = f2bf(fmaxf(acc[reg], 0.f));
    }

    int nbrC[4];
#pragma unroll
    for (int reg = 0; reg < 4; ++reg)
      nbrC[reg] = idxg[(size_t)(sn0 + og * 16 + g * 4 + reg) * K1_ + k];

    LDS_FENCE();  // P + relh visible to all lanes of this wave

    // ---- per-nt fused: G2 (relh@w2T) + G4 (P@langT) + register combine
    short8 a2[4];
#pragma unroll
    for (int kk = 0; kk < 4; ++kk)
      a2[kk] = *(const short8*)&relh[ln * 136 + kk * 32 + g * 8];
    short8 pa = *(const short8*)&P[ln * 48 + (g >> 1) * 24 + (g & 1) * 8];
#pragma unroll
    for (int nt = 0; nt < 8; ++nt) {
      f32x4 ro = {b2v[nt], b2v[nt], b2v[nt], b2v[nt]};
#pragma unroll
      for (int kk = 0; kk < 4; ++kk) {
        short8 bw =
            *(const short8*)&w2T_bf[(size_t)(nt * 16 + ln) * 128 + kk * 32 + g * 8];
        ro = __builtin_amdgcn_mfma_f32_16x16x32_bf16(a2[kk], bw, ro, 0, 0, 0);
      }
      f32x4 iv = {0.f, 0.f, 0.f, 0.f};
      short8 bl = *(const short8*)&langT_s[(nt * 16 + ln) * 40 + g * 8];
      iv = __builtin_amdgcn_mfma_f32_16x16x32_bf16(pa, bl, iv, 0, 0, 0);
#pragma unroll
      for (int reg = 0; reg < 4; ++reg) {
        float fv = fbase[(size_t)nbrC[reg] * D_ + nt * 16 + ln];
        o[nt][reg] += fv * iv[reg] * ro[reg];
      }
    }
  }

  // ---- cross-wave reduction (4 waves per object group) ----
  __syncthreads();  // all tile work done; arena free for reuse
  float* R = (float*)arena;  // [8 waves][128 cols][16 rows] f32
  {
    float* Rw = R + w * 2048;
#pragma unroll
    for (int nt = 0; nt < 8; ++nt)
      *(f32x4*)&Rw[(nt * 16 + ln) * 16 + g * 4] = o[nt];
  }
  __syncthreads();
  {
    float vs[2][4];
#pragma unroll
    for (int t = 0; t < 2; ++t) {
      int nt = q * 2 + t;
      int col = nt * 16 + ln;
      f32x4 sum = {0.f, 0.f, 0.f, 0.f};
#pragma unroll
      for (int w2 = 0; w2 < 4; ++w2) {
        f32x4 p = *(f32x4*)&R[(og * 4 + w2) * 2048 + col * 16 + g * 4];
        sum += p;
      }
#pragma unroll
      for (int reg = 0; reg < 4; ++reg) {
        int obj = og * 16 + g * 4 + reg;
        float v = sum[reg] + f_out[(size_t)(sn0 + obj) * D_ + col];
        outp[(size_t)(sn0 + obj) * D_ + col] = v;
        vs[t][reg] = v;
      }
    }
#pragma unroll
    for (int reg = 0; reg < 4; ++reg) {
      float sv = vs[0][reg] + vs[1][reg];
      sv += __shfl_xor(sv, 1);
      sv += __shfl_xor(sv, 2);
      sv += __shfl_xor(sv, 4);
      sv += __shfl_xor(sv, 8);
      if (ln == 0) atomicAdd(&score_s[og * 16 + g * 4 + reg], sv);
    }
  }
  __syncthreads();
  if (tid < CH_) score[sn0 + tid] = score_s[tid];
}

extern "C" void kernel_launch(void* const* d_in, const int* in_sizes, int n_in,
                              void* d_out, int out_size, void* d_ws,
                              size_t ws_size, hipStream_t stream) {
  const float* feat = (const float*)d_in[0];
  const float* coord = (const float*)d_in[1];
  const float* lang_feat = (const float*)d_in[2];
  const int* lang_len = (const int*)d_in[3];
  const float* rel_w1 = (const float*)d_in[4];
  const float* rel_b1 = (const float*)d_in[5];
  const float* rel_w2 = (const float*)d_in[6];
  const float* rel_b2 = (const float*)d_in[7];
  const float* lang_w1 = (const float*)d_in[8];
  const float* lang_b1 = (const float*)d_in[9];
  const float* lang_w2 = (const float*)d_in[10];
  const float* lang_b2 = (const float*)d_in[11];
  const float* feat_w1 = (const float*)d_in[12];
  const float* feat_b1 = (const float*)d_in[13];
  const float* feat_w2 = (const float*)d_in[14];
  const float* feat_b2 = (const float*)d_in[15];

  char* ws = (char*)d_ws;
  unsigned short* lang_bf = (unsigned short*)(ws);                  // 512 KB
  unsigned short* langT_bf = (unsigned short*)(ws + 524288);        // 512 KB
  float* f_out = (float*)(ws + 1048576);                            // 8 MB
  unsigned short* f_bf = (unsigned short*)(ws + 9437184);           // 4 MB
  int* idx = (int*)(ws + 13631488);                                 // ~1.1 MB
  float* rel10 = (float*)(ws + 14745600);                           // ~11.1 MB
  unsigned short* w2T_bf = (unsigned short*)(ws + 25886720);        // 32 KB
  unsigned short* w1T_bf = (unsigned short*)(ws + 25919488);        // 4 KB
  unsigned short* fw1T_bf = (unsigned short*)(ws + 25923584);       // 32 KB
  unsigned short* fw2T_bf = (unsigned short*)(ws + 25956352);       // 32 KB

  float* out = (float*)d_out;
  float* score = out + (size_t)S_ * N_ * D_;

  tar_prep_kernel<<<dim3(64), dim3(256), 0, stream>>>(
      rel_w1, rel_w2, feat_w1, feat_w2, w1T_bf, w2T_bf, fw1T_bf, fw2T_bf);
  tar_knn_kernel<<<dim3(S_ * N_), dim3(64), 0, stream>>>(coord, idx, rel10);
  tar_lang_mlp_kernel<<<dim3(S_ * L_), dim3(128), 0, stream>>>(
      lang_feat, lang_w1, lang_b1, lang_w2, lang_b2, lang_bf, langT_bf);
  tar_f_mlp_mfma<<<dim3(S_ * N_ / 64), dim3(256), 0, stream>>>(
      feat, fw1T_bf, feat_b1, fw2T_bf, feat_b2, f_out, f_bf);
  tar_main_mfma<<<dim3(S_ * (N_ / CH_)), dim3(512), 0, stream>>>(
      f_out, f_bf, lang_bf, langT_bf, idx, rel10, w1T_bf, w2T_bf, rel_b1,
      rel_b2, lang_len, out, score);
}

// Round 6
// 225.956 us; speedup vs baseline: 3.4824x; 1.2264x over previous
//
#include <hip/hip_runtime.h>
#include <math.h>

#define S_ 64
#define N_ 256
#define L_ 32
#define D_ 128
#define LID_ 256
#define K1_ 17
#define CH_ 32    // objects per main block
#define NW_ 8     // waves per main block

typedef __attribute__((ext_vector_type(8))) short short8;
typedef __attribute__((ext_vector_type(4))) float f32x4;

__device__ __forceinline__ unsigned short f2bf(float f) {
  unsigned int u = __float_as_uint(f);
  u += 0x7fffu + ((u >> 16) & 1u);
  return (unsigned short)(u >> 16);
}
__device__ __forceinline__ float bf2f(unsigned short h) {
  return __uint_as_float(((unsigned int)h) << 16);
}
// wave-level LDS fence: drain DS ops, then pin scheduler (rule #18 insurance)
#define LDS_FENCE()                                    \
  do {                                                 \
    asm volatile("s_waitcnt lgkmcnt(0)" ::: "memory"); \
    __builtin_amdgcn_sched_barrier(0);                 \
  } while (0)

// ---------------------------------------------------------------- KNN kernel
__global__ __launch_bounds__(64) void tar_knn_kernel(
    const float* __restrict__ coord, int* __restrict__ idx_out,
    float* __restrict__ rel10_out) {
  int b = blockIdx.x;
  int s = b >> 8;
  int n = b & 255;
  int lane = threadIdx.x;
  const float* cs = coord + (size_t)s * N_ * 3;
  float cx = cs[n * 3 + 0], cy = cs[n * 3 + 1], cz = cs[n * 3 + 2];
  float d[4];
  int jj[4];
#pragma unroll
  for (int q = 0; q < 4; ++q) {
    int j = q * 64 + lane;
    float dx = cs[j * 3 + 0] - cx;
    float dy = cs[j * 3 + 1] - cy;
    float dz = cs[j * 3 + 2] - cz;
    d[q] = dx * dx + dy * dy + dz * dz;
    jj[q] = j;
  }
  for (int k = 0; k < K1_; ++k) {
    float bd = 1e30f;
    int bj = 1 << 30;
#pragma unroll
    for (int q = 0; q < 4; ++q) {
      if (d[q] < bd || (d[q] == bd && jj[q] < bj)) { bd = d[q]; bj = jj[q]; }
    }
    for (int off = 32; off > 0; off >>= 1) {
      float od = __shfl_xor(bd, off);
      int oj = __shfl_xor(bj, off);
      if (od < bd || (od == bd && oj < bj)) { bd = od; bj = oj; }
    }
#pragma unroll
    for (int q = 0; q < 4; ++q)
      if (jj[q] == bj) d[q] = 1e30f;
    if (lane == 0) {
      idx_out[(size_t)b * K1_ + k] = bj;
      float nx = cs[bj * 3 + 0], ny = cs[bj * 3 + 1], nz = cs[bj * 3 + 2];
      float rx = nx - cx, ry = ny - cy, rz = nz - cz;
      float dist = sqrtf(rx * rx + ry * ry + rz * rz);
      float* r = rel10_out + ((size_t)b * K1_ + k) * 10;
      r[0] = nx; r[1] = ny; r[2] = nz;
      r[3] = cx; r[4] = cy; r[5] = cz;
      r[6] = rx; r[7] = ry; r[8] = rz; r[9] = dist;
    }
  }
}

// ---------------------------------------------------------------- lang MLP
__global__ __launch_bounds__(128) void tar_lang_mlp_kernel(
    const float* __restrict__ x, const float* __restrict__ w1,
    const float* __restrict__ b1, const float* __restrict__ w2,
    const float* __restrict__ b2, unsigned short* __restrict__ y_bf,
    unsigned short* __restrict__ yT_bf) {
  __shared__ float sx[LID_];
  __shared__ float sh[D_];
  int row = blockIdx.x, j = threadIdx.x;
  const float* xr = x + (size_t)row * LID_;
  sx[j] = xr[j];
  sx[j + 128] = xr[j + 128];
  __syncthreads();
  float acc = b1[j];
#pragma unroll 8
  for (int i = 0; i < LID_; ++i) acc += sx[i] * w1[i * D_ + j];
  sh[j] = fmaxf(acc, 0.f);
  __syncthreads();
  float acc2 = b2[j];
#pragma unroll 8
  for (int h = 0; h < D_; ++h) acc2 += sh[h] * w2[h * D_ + j];
  unsigned short hb = f2bf(acc2);
  y_bf[(size_t)row * D_ + j] = hb;
  int s = row >> 5, l = row & 31;
  yT_bf[((size_t)s * D_ + j) * L_ + l] = hb;
}

// ---------------------------------------------------------------- weight prep
__global__ __launch_bounds__(256) void tar_prep_kernel(
    const float* __restrict__ rw1, const float* __restrict__ rw2,
    const float* __restrict__ fw1, const float* __restrict__ fw2,
    unsigned short* __restrict__ w1T, unsigned short* __restrict__ w2T,
    unsigned short* __restrict__ fw1T, unsigned short* __restrict__ fw2T) {
  int t = blockIdx.x * 256 + threadIdx.x;  // 0..16383
  int k = t >> 7, n = t & 127;
  w2T[(size_t)n * 128 + k] = f2bf(rw2[(size_t)k * 128 + n]);
  fw1T[(size_t)n * 128 + k] = f2bf(fw1[(size_t)k * 128 + n]);
  fw2T[(size_t)n * 128 + k] = f2bf(fw2[(size_t)k * 128 + n]);
  if (t < 128 * 16) {
    int n2 = t >> 4, k2 = t & 15;
    w1T[(size_t)n2 * 16 + k2] = (k2 < 10) ? f2bf(rw1[(size_t)k2 * 128 + n2]) : 0;
  }
}

// ---------------------------------------------------------------- feat MLP (MFMA)
__global__ __launch_bounds__(256) void tar_f_mlp_mfma(
    const float* __restrict__ x, const unsigned short* __restrict__ fw1T,
    const float* __restrict__ b1, const unsigned short* __restrict__ fw2T,
    const float* __restrict__ b2, float* __restrict__ y,
    unsigned short* __restrict__ y_bf) {
  __shared__ unsigned short x_s[64 * 136];
  __shared__ unsigned short h_s[4][16 * 136];
  int base = blockIdx.x * 64;
  int tid = threadIdx.x;
  int w = tid >> 6, l = tid & 63, g = l >> 4, ln = l & 15;

  for (int i = tid; i < 64 * 32; i += 256) {
    int row = i >> 5, c4 = (i & 31) * 4;
    float4 v = *(const float4*)&x[(size_t)(base + row) * D_ + c4];
    unsigned short* dst = &x_s[row * 136 + c4];
    dst[0] = f2bf(v.x); dst[1] = f2bf(v.y);
    dst[2] = f2bf(v.z); dst[3] = f2bf(v.w);
  }
  __syncthreads();

  float b1v[8], b2v[8];
#pragma unroll
  for (int nt = 0; nt < 8; ++nt) {
    b1v[nt] = b1[nt * 16 + ln];
    b2v[nt] = b2[nt * 16 + ln];
  }

  short8 a1[4];
#pragma unroll
  for (int kk = 0; kk < 4; ++kk)
    a1[kk] = *(const short8*)&x_s[(w * 16 + ln) * 136 + kk * 32 + g * 8];
  unsigned short* hw = h_s[w];
#pragma unroll
  for (int nt = 0; nt < 8; ++nt) {
    f32x4 acc = {b1v[nt], b1v[nt], b1v[nt], b1v[nt]};
#pragma unroll
    for (int kk = 0; kk < 4; ++kk) {
      short8 bw =
          *(const short8*)&fw1T[(size_t)(nt * 16 + ln) * 128 + kk * 32 + g * 8];
      acc = __builtin_amdgcn_mfma_f32_16x16x32_bf16(a1[kk], bw, acc, 0, 0, 0);
    }
#pragma unroll
    for (int reg = 0; reg < 4; ++reg)
      hw[(g * 4 + reg) * 136 + nt * 16 + ln] = f2bf(fmaxf(acc[reg], 0.f));
  }
  LDS_FENCE();

  short8 a2[4];
#pragma unroll
  for (int kk = 0; kk < 4; ++kk)
    a2[kk] = *(const short8*)&hw[ln * 136 + kk * 32 + g * 8];
#pragma unroll
  for (int nt = 0; nt < 8; ++nt) {
    f32x4 acc = {b2v[nt], b2v[nt], b2v[nt], b2v[nt]};
#pragma unroll
    for (int kk = 0; kk < 4; ++kk) {
      short8 bw =
          *(const short8*)&fw2T[(size_t)(nt * 16 + ln) * 128 + kk * 32 + g * 8];
      acc = __builtin_amdgcn_mfma_f32_16x16x32_bf16(a2[kk], bw, acc, 0, 0, 0);
    }
#pragma unroll
    for (int reg = 0; reg < 4; ++reg) {
      int row = base + w * 16 + g * 4 + reg;
      int col = nt * 16 + ln;
      y[(size_t)row * D_ + col] = acc[reg];
      y_bf[(size_t)row * D_ + col] = f2bf(acc[reg]);
    }
  }
}

// ---------------------------------------------------------------- main MFMA
// block = (sentence, 32 objects), 8 waves = (og, h, q2):
//   og = obj group (16 objs), h = nt-half (4 of 8 col-tiles), q2 = k parity.
// Each wave: k = q2, q2+2, ... ; computes G3+softmax+G1 for its 16-obj tile
// (duplicated across the h-pair -- MFMA is cheap), then G2+G4+combine for its
// 4 col-tiles only -> o[4] = 16 VGPRs. Peak live regs ~60: fits without
// spills even at a 64-VGPR allocation (round-5 postmortem: spill traffic was
// ~450 MB HBM round-trip = the entire kernel duration).
__global__ __launch_bounds__(512, 2) void tar_main_mfma(
    const float* __restrict__ f_out, const unsigned short* __restrict__ f_bf,
    const unsigned short* __restrict__ lang_bf,
    const unsigned short* __restrict__ langT_bf, const int* __restrict__ idxg,
    const float* __restrict__ rel10g, const unsigned short* __restrict__ w1T_bf,
    const unsigned short* __restrict__ w2T_bf,
    const float* __restrict__ rel_b1, const float* __restrict__ rel_b2,
    const int* __restrict__ lang_len, float* __restrict__ outp,
    float* __restrict__ score) {
  // arena: lang_s [32][136]u16 @0 (8704) | langT_s [128][40]u16 @8704 (10240)
  //        w1T_s [128][24]u16 @18944 (6144) | relh 8x[16][136]u16 @25088
  //        P 8x[16][48]u16 @59904 (12288) -> 72192 B total;
  //        epilogue aliases arena as R = f32 8 x [64rows][20stride] (40960 B)
  __shared__ __align__(16) char arena[72192];
  __shared__ float score_s[CH_];

  unsigned short* lang_s = (unsigned short*)(arena);
  unsigned short* langT_s = (unsigned short*)(arena + 8704);
  unsigned short* w1T_s = (unsigned short*)(arena + 18944);

  int b = blockIdx.x;
  int s = b >> 3;
  int chunk = b & 7;
  int sn0 = s * N_ + chunk * CH_;
  int tid = threadIdx.x;
  int w = tid >> 6;
  int l = tid & 63;
  int g = l >> 4;
  int ln = l & 15;
  int og = w >> 2;        // object group (0/1)
  int h = (w >> 1) & 1;   // nt half: tiles h*4 .. h*4+3
  int q2 = w & 1;         // k parity
  int len = lang_len[s];

  unsigned short* relh = (unsigned short*)(arena + 25088 + w * 4352);
  unsigned short* P = (unsigned short*)(arena + 59904 + w * 1536);

  {
    int row = tid >> 4, c0 = (tid & 15) * 8;
    *(short8*)&lang_s[row * 136 + c0] =
        *(const short8*)&lang_bf[((size_t)s * L_ + row) * D_ + c0];
  }
  {
    int row = tid >> 2, c0 = (tid & 3) * 8;
    *(short8*)&langT_s[row * 40 + c0] =
        *(const short8*)&langT_bf[((size_t)s * D_ + row) * L_ + c0];
  }
  if (tid < 256) {
    int row = tid >> 1, c0 = (tid & 1) * 8;
    *(short8*)&w1T_s[row * 24 + c0] =
        *(const short8*)&w1T_bf[(size_t)row * 16 + c0];
  }
  if (tid < CH_) score_s[tid] = 0.f;
  __syncthreads();

  float b1v[8], b2v[4];
#pragma unroll
  for (int nt = 0; nt < 8; ++nt) b1v[nt] = rel_b1[nt * 16 + ln];
#pragma unroll
  for (int j = 0; j < 4; ++j) b2v[j] = rel_b2[(h * 4 + j) * 16 + ln];

  f32x4 o[4];
#pragma unroll
  for (int j = 0; j < 4; ++j) o[j] = (f32x4){0.f, 0.f, 0.f, 0.f};

  int objA = og * 16 + ln;
  const float* fbase = &f_out[(size_t)s * N_ * D_];

  for (int k = q2; k < K1_; k += 2) {
    LDS_FENCE();  // WAR: prior tile's P/relh reads done before restaging

    int nbrA = idxg[(size_t)(sn0 + objA) * K1_ + k];
    const unsigned short* fArow = &f_bf[((size_t)s * N_ + nbrA) * D_];

    // ---- G3: attn = f_nb @ lang^T  (M=16 objs, N=32 tokens, K=128)
    f32x4 at0 = {0.f, 0.f, 0.f, 0.f}, at1 = {0.f, 0.f, 0.f, 0.f};
#pragma unroll
    for (int kk = 0; kk < 4; ++kk) {
      short8 fA = *(const short8*)&fArow[kk * 32 + g * 8];
      short8 bb0 = *(const short8*)&lang_s[ln * 136 + kk * 32 + g * 8];
      short8 bb1 = *(const short8*)&lang_s[(16 + ln) * 136 + kk * 32 + g * 8];
      at0 = __builtin_amdgcn_mfma_f32_16x16x32_bf16(fA, bb0, at0, 0, 0, 0);
      at1 = __builtin_amdgcn_mfma_f32_16x16x32_bf16(fA, bb1, at1, 0, 0, 0);
    }
    // ---- softmax (ref-exact: softmax over 32, mask, renorm +1e-7)
#pragma unroll
    for (int reg = 0; reg < 4; ++reg) {
      float v0 = at0[reg], v1 = at1[reg];
      float mx = fmaxf(v0, v1);
      mx = fmaxf(mx, __shfl_xor(mx, 1));
      mx = fmaxf(mx, __shfl_xor(mx, 2));
      mx = fmaxf(mx, __shfl_xor(mx, 4));
      mx = fmaxf(mx, __shfl_xor(mx, 8));
      float e0 = expf(v0 - mx), e1 = expf(v1 - mx);
      float ss = e0 + e1;
      ss += __shfl_xor(ss, 1);
      ss += __shfl_xor(ss, 2);
      ss += __shfl_xor(ss, 4);
      ss += __shfl_xor(ss, 8);
      float p0 = (ln < len) ? e0 : 0.f;
      float p1 = (16 + ln < len) ? e1 : 0.f;
      float ms = p0 + p1;
      ms += __shfl_xor(ms, 1);
      ms += __shfl_xor(ms, 2);
      ms += __shfl_xor(ms, 4);
      ms += __shfl_xor(ms, 8);
      float inv = 1.0f / (ms + 1e-7f * ss);  // == ref algebra exactly
      int row = g * 4 + reg;
      P[row * 48 + ln] = f2bf(p0 * inv);
      P[row * 48 + 24 + ln] = f2bf(p1 * inv);
    }

    // ---- G1: relh = relu(rel10 @ w1 + b1)  (K padded 10->32)
    short8 a1v = {0, 0, 0, 0, 0, 0, 0, 0};
    {
      const float* r10 = &rel10g[((size_t)(sn0 + objA) * K1_ + k) * 10];
      if (g == 0) {
        float2 p0 = *(const float2*)(r10 + 0);
        float2 p1 = *(const float2*)(r10 + 2);
        float2 p2 = *(const float2*)(r10 + 4);
        float2 p3 = *(const float2*)(r10 + 6);
        a1v[0] = (short)f2bf(p0.x); a1v[1] = (short)f2bf(p0.y);
        a1v[2] = (short)f2bf(p1.x); a1v[3] = (short)f2bf(p1.y);
        a1v[4] = (short)f2bf(p2.x); a1v[5] = (short)f2bf(p2.y);
        a1v[6] = (short)f2bf(p3.x); a1v[7] = (short)f2bf(p3.y);
      } else if (g == 1) {
        float2 p4 = *(const float2*)(r10 + 8);
        a1v[0] = (short)f2bf(p4.x); a1v[1] = (short)f2bf(p4.y);
      }
    }
#pragma unroll
    for (int nt = 0; nt < 8; ++nt) {
      f32x4 acc = {b1v[nt], b1v[nt], b1v[nt], b1v[nt]};
      short8 bw = {0, 0, 0, 0, 0, 0, 0, 0};
      if (g < 2) bw = *(const short8*)&w1T_s[(nt * 16 + ln) * 24 + g * 8];
      acc = __builtin_amdgcn_mfma_f32_16x16x32_bf16(a1v, bw, acc, 0, 0, 0);
#pragma unroll
      for (int reg = 0; reg < 4; ++reg)
        relh[(g * 4 + reg) * 136 + nt * 16 + ln] = f2bf(fmaxf(acc[reg], 0.f));
    }

    int nbrC[4];
#pragma unroll
    for (int reg = 0; reg < 4; ++reg)
      nbrC[reg] = idxg[(size_t)(sn0 + og * 16 + g * 4 + reg) * K1_ + k];

    LDS_FENCE();  // P + relh visible to all lanes of this wave

    // ---- per-j fused: G2 (relh@w2T) + G4 (P@langT) + register combine,
    //      only this wave's 4 col-tiles (nt = h*4+j)
    short8 pa = *(const short8*)&P[ln * 48 + (g >> 1) * 24 + (g & 1) * 8];
#pragma unroll
    for (int j = 0; j < 4; ++j) {
      int nt = h * 4 + j;
      f32x4 ro = {b2v[j], b2v[j], b2v[j], b2v[j]};
#pragma unroll
      for (int kk = 0; kk < 4; ++kk) {
        short8 a2 = *(const short8*)&relh[ln * 136 + kk * 32 + g * 8];
        short8 bw =
            *(const short8*)&w2T_bf[(size_t)(nt * 16 + ln) * 128 + kk * 32 + g * 8];
        ro = __builtin_amdgcn_mfma_f32_16x16x32_bf16(a2, bw, ro, 0, 0, 0);
      }
      f32x4 iv = {0.f, 0.f, 0.f, 0.f};
      short8 bl = *(const short8*)&langT_s[(nt * 16 + ln) * 40 + g * 8];
      iv = __builtin_amdgcn_mfma_f32_16x16x32_bf16(pa, bl, iv, 0, 0, 0);
#pragma unroll
      for (int reg = 0; reg < 4; ++reg) {
        float fv = fbase[(size_t)nbrC[reg] * D_ + nt * 16 + ln];
        o[j][reg] += fv * iv[reg] * ro[reg];
      }
    }
  }

  // ---- cross-wave reduction (q2 partner pairs) ----
  __syncthreads();  // all tile work done; arena free for reuse
  float* R = (float*)arena;  // 8 x [64 rows][stride 20] f32 (padded banks)
  {
    float* Rw = R + w * 1280;
#pragma unroll
    for (int j = 0; j < 4; ++j)
      *(f32x4*)&Rw[(j * 16 + ln) * 20 + g * 4] = o[j];
  }
  __syncthreads();
  {
    int wp = og * 4 + h * 2;  // partner pair base (q2 = 0,1)
    float vs[2][4];
#pragma unroll
    for (int t = 0; t < 2; ++t) {
      int j = q2 * 2 + t;
      int col = (h * 4 + j) * 16 + ln;
      f32x4 sum = *(f32x4*)&R[wp * 1280 + (j * 16 + ln) * 20 + g * 4];
      sum += *(f32x4*)&R[(wp + 1) * 1280 + (j * 16 + ln) * 20 + g * 4];
#pragma unroll
      for (int reg = 0; reg < 4; ++reg) {
        int obj = og * 16 + g * 4 + reg;
        float v = sum[reg] + f_out[(size_t)(sn0 + obj) * D_ + col];
        outp[(size_t)(sn0 + obj) * D_ + col] = v;
        vs[t][reg] = v;
      }
    }
#pragma unroll
    for (int reg = 0; reg < 4; ++reg) {
      float sv = vs[0][reg] + vs[1][reg];
      sv += __shfl_xor(sv, 1);
      sv += __shfl_xor(sv, 2);
      sv += __shfl_xor(sv, 4);
      sv += __shfl_xor(sv, 8);
      if (ln == 0) atomicAdd(&score_s[og * 16 + g * 4 + reg], sv);
    }
  }
  __syncthreads();
  if (tid < CH_) score[sn0 + tid] = score_s[tid];
}

extern "C" void kernel_launch(void* const* d_in, const int* in_sizes, int n_in,
                              void* d_out, int out_size, void* d_ws,
                              size_t ws_size, hipStream_t stream) {
  const float* feat = (const float*)d_in[0];
  const float* coord = (const float*)d_in[1];
  const float* lang_feat = (const float*)d_in[2];
  const int* lang_len = (const int*)d_in[3];
  const float* rel_w1 = (const float*)d_in[4];
  const float* rel_b1 = (const float*)d_in[5];
  const float* rel_w2 = (const float*)d_in[6];
  const float* rel_b2 = (const float*)d_in[7];
  const float* lang_w1 = (const float*)d_in[8];
  const float* lang_b1 = (const float*)d_in[9];
  const float* lang_w2 = (const float*)d_in[10];
  const float* lang_b2 = (const float*)d_in[11];
  const float* feat_w1 = (const float*)d_in[12];
  const float* feat_b1 = (const float*)d_in[13];
  const float* feat_w2 = (const float*)d_in[14];
  const float* feat_b2 = (const float*)d_in[15];

  char* ws = (char*)d_ws;
  unsigned short* lang_bf = (unsigned short*)(ws);                  // 512 KB
  unsigned short* langT_bf = (unsigned short*)(ws + 524288);        // 512 KB
  float* f_out = (float*)(ws + 1048576);                            // 8 MB
  unsigned short* f_bf = (unsigned short*)(ws + 9437184);           // 4 MB
  int* idx = (int*)(ws + 13631488);                                 // ~1.1 MB
  float* rel10 = (float*)(ws + 14745600);                           // ~11.1 MB
  unsigned short* w2T_bf = (unsigned short*)(ws + 25886720);        // 32 KB
  unsigned short* w1T_bf = (unsigned short*)(ws + 25919488);        // 4 KB
  unsigned short* fw1T_bf = (unsigned short*)(ws + 25923584);       // 32 KB
  unsigned short* fw2T_bf = (unsigned short*)(ws + 25956352);       // 32 KB

  float* out = (float*)d_out;
  float* score = out + (size_t)S_ * N_ * D_;

  tar_prep_kernel<<<dim3(64), dim3(256), 0, stream>>>(
      rel_w1, rel_w2, feat_w1, feat_w2, w1T_bf, w2T_bf, fw1T_bf, fw2T_bf);
  tar_knn_kernel<<<dim3(S_ * N_), dim3(64), 0, stream>>>(coord, idx, rel10);
  tar_lang_mlp_kernel<<<dim3(S_ * L_), dim3(128), 0, stream>>>(
      lang_feat, lang_w1, lang_b1, lang_w2, lang_b2, lang_bf, langT_bf);
  tar_f_mlp_mfma<<<dim3(S_ * N_ / 64), dim3(256), 0, stream>>>(
      feat, fw1T_bf, feat_b1, fw2T_bf, feat_b2, f_out, f_bf);
  tar_main_mfma<<<dim3(S_ * (N_ / CH_)), dim3(512), 0, stream>>>(
      f_out, f_bf, lang_bf, langT_bf, idx, rel10, w1T_bf, w2T_bf, rel_b1,
      rel_b2, lang_len, out, score);
}